// Round 3
// baseline (261.527 us; speedup 1.0000x reference)
//
#include <hip/hip_runtime.h>
#include <hip/hip_cooperative_groups.h>

namespace cg = cooperative_groups;

#define HEADS 8
#define HDIM 32
#define NTOK 1024
#define CDIM 256
#define BATCH 16
#define ATT_SCALE 0.17677669529663687f  // 32^-0.5
#define L2E 1.4426950408889634f
#define BSTR 1544   // bias copy stride (floats): 16B-aligned; 1544%32=8 -> ~2-way reads

typedef __attribute__((ext_vector_type(8))) short bf16x8;   // 8 bf16, 4 VGPRs
typedef __attribute__((ext_vector_type(4))) float f32x4;    // MFMA C/D

__device__ __forceinline__ unsigned short f2bf(float f) {
    unsigned int u = __float_as_uint(f);
    return (unsigned short)((u + 0x7fffu + ((u >> 16) & 1u)) >> 16);  // RNE
}

// pack two f32 -> (bf16(lo) | bf16(hi)<<16) in one instruction (no builtin on gfx950)
__device__ __forceinline__ unsigned cvt_pk_bf16(float lo, float hi) {
    unsigned r;
    asm("v_cvt_pk_bf16_f32 %0, %1, %2" : "=v"(r) : "v"(lo), "v"(hi));
    return r;
}

// ---------------------------------------------------------------------------
// Single persistent cooperative kernel, 256 blocks x 1024 threads (1 block/CU
// at 152.6 KB LDS -> full co-residency).  Grid syncs replace the inter-kernel
// gaps that accounted for ~50-60 us of the 3-kernel pipeline.
//   Phase 1: x (b,c,n) f32 -> xt16 (b,n,c) bf16 (4 transpose tiles per block);
//            blocks 0-15 also convert weights (Wk pre-scaled by SCALE*L2E).
//   Phase 2: fused QKV + flash attention (identical to the 77us R1 kernel:
//            bias*L2E in LDS 4-copy table, K+bias 1-iter prefetch, cvt_pk
//            packing, setprio around MFMA clusters, fragment-major K/V).
//   Phase 3: output projection re-tiled as 1024 sub-blocks of 64c x 64p
//            (4 per block, 4 waves each).  XCD mapping keeps ao16[b] reads
//            on the XCD that wrote them.
// ---------------------------------------------------------------------------
__global__ __launch_bounds__(1024, 4) void fused_kernel(
    const float* __restrict__ x,
    const float* __restrict__ Wq, const float* __restrict__ Wk,
    const float* __restrict__ Wv, const float* __restrict__ Wo,
    const float* __restrict__ bo, const float* __restrict__ rel_bias,
    unsigned short* __restrict__ w16, unsigned short* __restrict__ xt16,
    unsigned short* __restrict__ ao16, float* __restrict__ y)
{
    __shared__ __align__(16) unsigned char smem[65536 + 65536 + BSTR * 4 * 4];
    const int t = threadIdx.x;

    // ================= Phase 1: transpose + weight convert =================
    {
        const int B = blockIdx.x;
        float (*tile4)[64][65] = (float(*)[64][65])smem;
        const int slot = t >> 8, tt = t & 255;
        const int T = B * 4 + slot;                 // 0..1023 tiles
        const int b1 = T >> 6;
        const int ctf = ((T >> 4) & 3) * 64;
        const int ntf = (T & 15) * 64;
        const float* xb1 = x + ((size_t)b1 * CDIM + ctf) * NTOK + ntf;
        const int cc = tt >> 4, n4 = (tt & 15) * 4;
        #pragma unroll
        for (int i = 0; i < 4; ++i) {
            float4 v = *(const float4*)&xb1[(size_t)(cc + 16 * i) * NTOK + n4];
            tile4[slot][cc + 16 * i][n4]     = v.x;
            tile4[slot][cc + 16 * i][n4 + 1] = v.y;
            tile4[slot][cc + 16 * i][n4 + 2] = v.z;
            tile4[slot][cc + 16 * i][n4 + 3] = v.w;
        }
        // weights: blocks 0..15, no LDS involved
        if (B < 16) {
            const int which = B & 3;
            const float* src = (which == 0) ? Wq : ((which == 1) ? Wk : ((which == 2) ? Wv : Wo));
            const float scale = (which == 1) ? (ATT_SCALE * L2E) : 1.0f;
            const int base = ((B >> 2) * 1024 + t) * 16;
            #pragma unroll
            for (int i = 0; i < 4; ++i) {
                const int idx = base + i * 4;
                float4 v = *(const float4*)&src[idx];
                union { unsigned short h[4]; uint2 u; } pk;
                pk.h[0] = f2bf(v.x * scale); pk.h[1] = f2bf(v.y * scale);
                pk.h[2] = f2bf(v.z * scale); pk.h[3] = f2bf(v.w * scale);
                *(uint2*)&w16[(size_t)which * 65536 + idx] = pk.u;
            }
        }
        __syncthreads();
        const int c0 = (tt & 7) * 8;          // 8 c-values per 16B store
        #pragma unroll
        for (int i = 0; i < 2; ++i) {
            const int nl = (tt >> 3) + 32 * i;
            union { unsigned short h[8]; uint4 u; } pk;
            #pragma unroll
            for (int j = 0; j < 8; ++j) pk.h[j] = f2bf(tile4[slot][c0 + j][nl]);
            *(uint4*)&xt16[((size_t)b1 * NTOK + ntf + nl) * CDIM + ctf + c0] = pk.u;
        }
    }

    cg::this_grid().sync();

    // ================= Phase 2: fused QKV + flash attention =================
    {
        unsigned short* k_s   = (unsigned short*)smem;             // 64 frags x 512 shorts
        unsigned short* v_s   = (unsigned short*)(smem + 65536);   // 64 frags x 512 shorts
        unsigned short* q_s   = (unsigned short*)(smem + 65536);   // overlay (512 x 32)
        float*          bias4 = (float*)(smem + 131072);           // [4][BSTR]

        const int id   = blockIdx.x;                    // 0..255
        const int bh_i = (id & 7) * 16 + (id >> 4);     // XCD x owns bh [16x,16x+16)
        const int half = (id >> 3) & 1;
        const int b = bh_i >> 3, h = bh_i & 7;

        const int wid = t >> 6, lane = t & 63;
        const int g = lane >> 4, ln = lane & 15;
        const int qb = half * 512 + wid * 32;           // wave's 32 queries

        const unsigned short* xb  = xt16 + (size_t)b * NTOK * CDIM;
        const unsigned short* wqh = w16 + (size_t)(h * 32) * CDIM;
        const unsigned short* wkh = w16 + 65536 + (size_t)(h * 32) * CDIM;
        const unsigned short* wvh = w16 + 2 * 65536 + (size_t)(h * 32) * CDIM;

        // ---- bias*log2e -> 4 shift-aligned copies, trimmed to block range ----
        {
            const int START = 544 - 512 * half;         // 4-aligned window base
            const float* brow = rel_bias + (size_t)h * 3969;
            for (int i = t; i < 1540; i += 1024) {
                #pragma unroll
                for (int a = 0; a < 4; ++a)
                    bias4[a * BSTR + i] = brow[START + a + i] * L2E;
            }
        }

        // ---- Stage 1a: Q GEMM — rows [qb,+32); write+read via q_s ----
        bf16x8 aq0, aq1;
        {
            f32x4 acc[2][2];
            #pragma unroll
            for (int m = 0; m < 2; ++m)
                #pragma unroll
                for (int n = 0; n < 2; ++n) acc[m][n] = (f32x4){0.f, 0.f, 0.f, 0.f};
            #pragma unroll
            for (int kt = 0; kt < CDIM; kt += 32) {
                bf16x8 a[2], w2[2];
                #pragma unroll
                for (int m = 0; m < 2; ++m)
                    a[m] = *(const bf16x8*)&xb[(size_t)(qb + m * 16 + ln) * CDIM + kt + g * 8];
                #pragma unroll
                for (int n = 0; n < 2; ++n)
                    w2[n] = *(const bf16x8*)&wqh[(size_t)(n * 16 + ln) * CDIM + kt + g * 8];
                #pragma unroll
                for (int m = 0; m < 2; ++m)
                    #pragma unroll
                    for (int n = 0; n < 2; ++n)
                        acc[m][n] = __builtin_amdgcn_mfma_f32_16x16x32_bf16(a[m], w2[n], acc[m][n], 0, 0, 0);
            }
            const int lr = wid * 32;
            #pragma unroll
            for (int m = 0; m < 2; ++m)
                #pragma unroll
                for (int n = 0; n < 2; ++n)
                    #pragma unroll
                    for (int r = 0; r < 4; ++r)
                        q_s[(size_t)(lr + m * 16 + g * 4 + r) * HDIM + n * 16 + ln] = f2bf(acc[m][n][r]);
            aq0 = *(const bf16x8*)&q_s[(size_t)(lr + ln) * HDIM + g * 8];
            aq1 = *(const bf16x8*)&q_s[(size_t)(lr + 16 + ln) * HDIM + g * 8];
        }

        __syncthreads();   // all q_s reads done before V overwrites the region

        // ---- Stage 1b: fused K+V GEMM — shared x fragments ----
        {
            const int tr = wid * 64;
            f32x4 ak[4][2], av[2][4];
            #pragma unroll
            for (int m = 0; m < 4; ++m)
                #pragma unroll
                for (int n = 0; n < 2; ++n) {
                    ak[m][n] = (f32x4){0.f, 0.f, 0.f, 0.f};
                    av[n][m] = (f32x4){0.f, 0.f, 0.f, 0.f};
                }
            #pragma unroll
            for (int kt = 0; kt < CDIM; kt += 32) {
                bf16x8 xf[4], wkf[2], wvf[2];
                #pragma unroll
                for (int m = 0; m < 4; ++m)
                    xf[m] = *(const bf16x8*)&xb[(size_t)(tr + m * 16 + ln) * CDIM + kt + g * 8];
                #pragma unroll
                for (int n = 0; n < 2; ++n) {
                    wkf[n] = *(const bf16x8*)&wkh[(size_t)(n * 16 + ln) * CDIM + kt + g * 8];
                    wvf[n] = *(const bf16x8*)&wvh[(size_t)(n * 16 + ln) * CDIM + kt + g * 8];
                }
                #pragma unroll
                for (int m = 0; m < 4; ++m) {
                    ak[m][0] = __builtin_amdgcn_mfma_f32_16x16x32_bf16(xf[m], wkf[0], ak[m][0], 0, 0, 0);
                    ak[m][1] = __builtin_amdgcn_mfma_f32_16x16x32_bf16(xf[m], wkf[1], ak[m][1], 0, 0, 0);
                    av[0][m] = __builtin_amdgcn_mfma_f32_16x16x32_bf16(wvf[0], xf[m], av[0][m], 0, 0, 0);
                    av[1][m] = __builtin_amdgcn_mfma_f32_16x16x32_bf16(wvf[1], xf[m], av[1][m], 0, 0, 0);
                }
            }
            // K store, fragment-major.
            #pragma unroll
            for (int m = 0; m < 4; ++m) {
                const int fbase = (2 * wid + (m >> 1)) * 2 + (g & 1);
                #pragma unroll
                for (int n = 0; n < 2; ++n) {
                    const int lhi = (2 * n + (ln >> 3)) * 16 + ((m & 1) * 2 + (g >> 1)) * 4;
                    #pragma unroll
                    for (int r = 0; r < 4; ++r)
                        k_s[fbase * 512 + (lhi + r) * 8 + (ln & 7)] = f2bf(ak[m][n][r]);
                }
            }
            // V store, fragment-major.
            #pragma unroll
            for (int n = 0; n < 2; ++n)
                #pragma unroll
                for (int m = 0; m < 4; ++m) {
                    const int fr  = (2 * wid + (m >> 1)) * 2 + n;
                    const int lnb = ((m & 1) * 2 + (ln >> 3)) * 16 + g * 4;
                    #pragma unroll
                    for (int r = 0; r < 4; ++r)
                        v_s[fr * 512 + (lnb + r) * 8 + (ln & 7)] = f2bf(av[n][m][r]);
                }
        }

        __syncthreads();   // K, V, bias all LDS-resident

        // ---- Stage 2: attention main loop ----
        const int boffL = 512 + 8 * g - wid * 32 - ln;   // local bias offset
        const int ba = boffL & 3;
        const float* bb = &bias4[ba * BSTR + (boffL - ba)];
        const unsigned short* kfp = k_s + lane * 8;      // frag stride 512 shorts
        const unsigned short* vfp = v_s + lane * 8;

        f32x4 o00 = {0.f,0.f,0.f,0.f}, o01 = {0.f,0.f,0.f,0.f};
        f32x4 o10 = {0.f,0.f,0.f,0.f}, o11 = {0.f,0.f,0.f,0.f};
        f32x4 ls0 = {0.f,0.f,0.f,0.f}, ls1 = {0.f,0.f,0.f,0.f};
        const short one_bf = (short)0x3F80;
        const bf16x8 ones = {one_bf,one_bf,one_bf,one_bf,one_bf,one_bf,one_bf,one_bf};

        // prologue: iter-0 K fragments + bias C-operands
        bf16x8 kf0 = *(const bf16x8*)&kfp[0];
        bf16x8 kf1 = *(const bf16x8*)&kfp[512];
        f32x4  cA0 = *(const f32x4*)&bb[0];
        f32x4  cA1 = *(const f32x4*)&bb[4];
        f32x4  cB0 = *(const f32x4*)&bb[-16];
        f32x4  cB1 = *(const f32x4*)&bb[-12];

        for (int kb = 0; kb < NTOK; kb += 32) {
            const int fi = (kb >> 5) * 2;
            const bf16x8 vA0 = *(const bf16x8*)&vfp[fi * 512];
            const bf16x8 vA1 = *(const bf16x8*)&vfp[(fi + 1) * 512];
            const int kn = (kb + 32) & (NTOK - 1);
            const int fn = (kn >> 5) * 2;
            const bf16x8 nk0 = *(const bf16x8*)&kfp[fn * 512];
            const bf16x8 nk1 = *(const bf16x8*)&kfp[(fn + 1) * 512];
            const f32x4  nA0 = *(const f32x4*)&bb[kn];
            const f32x4  nA1 = *(const f32x4*)&bb[kn + 4];
            const f32x4  nB0 = *(const f32x4*)&bb[kn - 16];
            const f32x4  nB1 = *(const f32x4*)&bb[kn - 12];

            __builtin_amdgcn_s_setprio(1);
            f32x4 s00 = __builtin_amdgcn_mfma_f32_16x16x32_bf16(kf0, aq0, cA0, 0, 0, 0);
            f32x4 s01 = __builtin_amdgcn_mfma_f32_16x16x32_bf16(kf1, aq0, cA1, 0, 0, 0);
            f32x4 s10 = __builtin_amdgcn_mfma_f32_16x16x32_bf16(kf0, aq1, cB0, 0, 0, 0);
            f32x4 s11 = __builtin_amdgcn_mfma_f32_16x16x32_bf16(kf1, aq1, cB1, 0, 0, 0);
            __builtin_amdgcn_s_setprio(0);

            union { unsigned u4[4]; bf16x8 v; } ap0, ap1;
            ap0.u4[0] = cvt_pk_bf16(__builtin_amdgcn_exp2f(s00[0]), __builtin_amdgcn_exp2f(s00[1]));
            ap0.u4[1] = cvt_pk_bf16(__builtin_amdgcn_exp2f(s00[2]), __builtin_amdgcn_exp2f(s00[3]));
            ap0.u4[2] = cvt_pk_bf16(__builtin_amdgcn_exp2f(s01[0]), __builtin_amdgcn_exp2f(s01[1]));
            ap0.u4[3] = cvt_pk_bf16(__builtin_amdgcn_exp2f(s01[2]), __builtin_amdgcn_exp2f(s01[3]));
            ap1.u4[0] = cvt_pk_bf16(__builtin_amdgcn_exp2f(s10[0]), __builtin_amdgcn_exp2f(s10[1]));
            ap1.u4[1] = cvt_pk_bf16(__builtin_amdgcn_exp2f(s10[2]), __builtin_amdgcn_exp2f(s10[3]));
            ap1.u4[2] = cvt_pk_bf16(__builtin_amdgcn_exp2f(s11[0]), __builtin_amdgcn_exp2f(s11[1]));
            ap1.u4[3] = cvt_pk_bf16(__builtin_amdgcn_exp2f(s11[2]), __builtin_amdgcn_exp2f(s11[3]));

            __builtin_amdgcn_s_setprio(1);
            o00 = __builtin_amdgcn_mfma_f32_16x16x32_bf16(ap0.v, vA0, o00, 0, 0, 0);
            o01 = __builtin_amdgcn_mfma_f32_16x16x32_bf16(ap0.v, vA1, o01, 0, 0, 0);
            ls0 = __builtin_amdgcn_mfma_f32_16x16x32_bf16(ap0.v, ones, ls0, 0, 0, 0);
            o10 = __builtin_amdgcn_mfma_f32_16x16x32_bf16(ap1.v, vA0, o10, 0, 0, 0);
            o11 = __builtin_amdgcn_mfma_f32_16x16x32_bf16(ap1.v, vA1, o11, 0, 0, 0);
            ls1 = __builtin_amdgcn_mfma_f32_16x16x32_bf16(ap1.v, ones, ls1, 0, 0, 0);
            __builtin_amdgcn_s_setprio(0);

            kf0 = nk0; kf1 = nk1;
            cA0 = nA0; cA1 = nA1; cB0 = nB0; cB1 = nB1;
        }

        #pragma unroll
        for (int r = 0; r < 4; ++r) {
            float i0 = 1.f / ls0[r], i1 = 1.f / ls1[r];
            o00[r] *= i0; o01[r] *= i0;
            o10[r] *= i1; o11[r] *= i1;
        }

        __syncthreads();   // all waves done with k_s; overlay otr on K region
        unsigned short (*otr)[32][40] = (unsigned short(*)[32][40])smem;
        #pragma unroll
        for (int r = 0; r < 4; ++r) {
            otr[wid][g * 4 + r][ln]           = f2bf(o00[r]);
            otr[wid][g * 4 + r][16 + ln]      = f2bf(o01[r]);
            otr[wid][16 + g * 4 + r][ln]      = f2bf(o10[r]);
            otr[wid][16 + g * 4 + r][16 + ln] = f2bf(o11[r]);
        }
        // same-wave region: DS in-order, no barrier.
        const int row = lane >> 1;
        const int ch  = (lane & 1) * 16;
        uint4 st0 = *(uint4*)&otr[wid][row][ch];
        uint4 st1 = *(uint4*)&otr[wid][row][ch + 8];
        unsigned short* dst = &ao16[((size_t)b * NTOK + qb + row) * CDIM + h * HDIM + ch];
        *(uint4*)dst     = st0;
        *(uint4*)&dst[8] = st1;
    }

    cg::this_grid().sync();

    // ================= Phase 3: output projection =================
    {
        const int t256 = t & 255, sub = t >> 8;
        const int sid = blockIdx.x * 4 + sub;          // 0..1023 sub-blocks
        const int b3   = (sid & 7) * 2 + ((sid >> 3) & 1);   // same-XCD as ao16 writer
        const int rest = sid >> 4;                     // 0..63
        const int ct3 = (rest & 3) * 64;
        const int pt3 = (rest >> 2) * 64;              // 16 p-tiles of 64
        const int wid3 = t256 >> 6, lane3 = t256 & 63;
        const int g3 = lane3 >> 4, ln3 = lane3 & 15;
        const int cb2 = ct3 + (wid3 & 1) * 32;
        const int pb  = pt3 + (wid3 >> 1) * 32;
        const unsigned short* ab   = ao16 + (size_t)b3 * NTOK * CDIM;
        const unsigned short* wo16 = w16 + 3 * 65536;

        f32x4 acc[2][2];
        #pragma unroll
        for (int n = 0; n < 2; ++n)
            #pragma unroll
            for (int m = 0; m < 2; ++m) acc[n][m] = (f32x4){0.f, 0.f, 0.f, 0.f};

        #pragma unroll
        for (int kt = 0; kt < CDIM; kt += 32) {
            bf16x8 aw[2], bx[2];
            #pragma unroll
            for (int n = 0; n < 2; ++n)
                aw[n] = *(const bf16x8*)&wo16[(size_t)(cb2 + n * 16 + ln3) * CDIM + kt + g3 * 8];
            #pragma unroll
            for (int m = 0; m < 2; ++m)
                bx[m] = *(const bf16x8*)&ab[(size_t)(pb + m * 16 + ln3) * CDIM + kt + g3 * 8];
            #pragma unroll
            for (int n = 0; n < 2; ++n)
                #pragma unroll
                for (int m = 0; m < 2; ++m)
                    acc[n][m] = __builtin_amdgcn_mfma_f32_16x16x32_bf16(aw[n], bx[m], acc[n][m], 0, 0, 0);
        }
        #pragma unroll
        for (int n = 0; n < 2; ++n)
            #pragma unroll
            for (int r = 0; r < 4; ++r) {
                const int c = cb2 + n * 16 + g3 * 4 + r;
                const float bias = bo[c];
                #pragma unroll
                for (int m = 0; m < 2; ++m)
                    y[((size_t)b3 * CDIM + c) * NTOK + pb + m * 16 + ln3] = acc[n][m][r] + bias;
            }
    }
}

// ---------------------------------------------------------------------------
extern "C" void kernel_launch(void* const* d_in, const int* in_sizes, int n_in,
                              void* d_out, int out_size, void* d_ws, size_t ws_size,
                              hipStream_t stream) {
    const float* x        = (const float*)d_in[0];
    const float* Wq       = (const float*)d_in[1];
    const float* Wk       = (const float*)d_in[2];
    const float* Wv       = (const float*)d_in[3];
    const float* Wo       = (const float*)d_in[4];
    const float* bo       = (const float*)d_in[5];
    const float* rel_bias = (const float*)d_in[6];
    (void)in_sizes; (void)n_in; (void)ws_size; (void)out_size;
    // d_in[7] = rel_idx: unused — bias index computed analytically (j - p + 1056)

    unsigned short* ws16 = (unsigned short*)d_ws;
    unsigned short* xt16 = ws16;                              // 8 MB
    unsigned short* ao16 = ws16 + (size_t)4 * 1024 * 1024;    // 8 MB
    unsigned short* w16  = ws16 + (size_t)8 * 1024 * 1024;    // 512 KB
    float* y = (float*)d_out;

    void* args[] = {
        (void*)&x, (void*)&Wq, (void*)&Wk, (void*)&Wv, (void*)&Wo,
        (void*)&bo, (void*)&rel_bias, (void*)&w16, (void*)&xt16,
        (void*)&ao16, (void*)&y
    };
    hipLaunchCooperativeKernel((void*)fused_kernel, dim3(256), dim3(1024),
                               args, 0, stream);
}

// Round 4
// 194.977 us; speedup vs baseline: 1.3413x; 1.3413x over previous
//
#include <hip/hip_runtime.h>

#define HEADS 8
#define HDIM 32
#define NTOK 1024
#define CDIM 256
#define BATCH 16
#define ATT_SCALE 0.17677669529663687f  // 32^-0.5
#define L2E 1.4426950408889634f
#define BSTR 1544   // bias copy stride (floats): 16B-aligned; 1544%32=8 -> ~2-way reads

typedef __attribute__((ext_vector_type(8))) short bf16x8;   // 8 bf16, 4 VGPRs
typedef __attribute__((ext_vector_type(4))) float f32x4;    // MFMA C/D

__device__ __forceinline__ unsigned short f2bf(float f) {
    unsigned int u = __float_as_uint(f);
    return (unsigned short)((u + 0x7fffu + ((u >> 16) & 1u)) >> 16);  // RNE
}

// pack two f32 -> (bf16(lo) | bf16(hi)<<16) in one instruction (no builtin on gfx950)
__device__ __forceinline__ unsigned cvt_pk_bf16(float lo, float hi) {
    unsigned r;
    asm("v_cvt_pk_bf16_f32 %0, %1, %2" : "=v"(r) : "v"(lo), "v"(hi));
    return r;
}

// ---------------------------------------------------------------------------
// Prep (fused): z<16 -> x (b,c,n) fp32 -> xt16 (b,n,c) bf16;  z==16 -> weights
// fp32 -> bf16.  Wk pre-scaled by ATT_SCALE*log2(e): S-MFMA output lands in
// log2 domain; bias (also *log2e) rides in the MFMA C operand; exp = v_exp_f32.
// ---------------------------------------------------------------------------
__global__ __launch_bounds__(256) void prep_kernel(
    const float* __restrict__ x,
    const float* __restrict__ Wq, const float* __restrict__ Wk,
    const float* __restrict__ Wv, const float* __restrict__ Wo,
    unsigned short* __restrict__ w16, unsigned short* __restrict__ xt16)
{
    const int t = threadIdx.x;
    if (blockIdx.z == 16) {
        const int which = blockIdx.y;
        const float* src = (which == 0) ? Wq : ((which == 1) ? Wk : ((which == 2) ? Wv : Wo));
        const float scale = (which == 1) ? (ATT_SCALE * L2E) : 1.0f;
        const int base = (blockIdx.x * 256 + t) * 16;
        #pragma unroll
        for (int i = 0; i < 4; ++i) {
            const int idx = base + i * 4;
            float4 v = *(const float4*)&src[idx];
            union { unsigned short h[4]; uint2 u; } pk;
            pk.h[0] = f2bf(v.x * scale); pk.h[1] = f2bf(v.y * scale);
            pk.h[2] = f2bf(v.z * scale); pk.h[3] = f2bf(v.w * scale);
            *(uint2*)&w16[(size_t)which * 65536 + idx] = pk.u;
        }
        return;
    }
    __shared__ float tile[64][65];
    const int b = blockIdx.z, ct = blockIdx.y * 64, nt = blockIdx.x * 64;
    const float* xb = x + ((size_t)b * CDIM + ct) * NTOK + nt;
    const int cc = t >> 4, n4 = (t & 15) * 4;
    #pragma unroll
    for (int i = 0; i < 4; ++i) {
        float4 v = *(const float4*)&xb[(size_t)(cc + 16 * i) * NTOK + n4];
        tile[cc + 16 * i][n4]     = v.x;
        tile[cc + 16 * i][n4 + 1] = v.y;
        tile[cc + 16 * i][n4 + 2] = v.z;
        tile[cc + 16 * i][n4 + 3] = v.w;
    }
    __syncthreads();
    const int c0 = (t & 7) * 8;          // 8 c-values per 16B store
    #pragma unroll
    for (int i = 0; i < 2; ++i) {
        const int nl = (t >> 3) + 32 * i;
        union { unsigned short h[8]; uint4 u; } pk;
        #pragma unroll
        for (int j = 0; j < 8; ++j) pk.h[j] = f2bf(tile[c0 + j][nl]);
        *(uint4*)&xt16[((size_t)b * NTOK + nt + nl) * CDIM + ct + c0] = pk.u;
    }
}

// ---------------------------------------------------------------------------
// Fused QKV + flash attention.  Block = (b, h, query-half): 1024 thr/16 waves.
//  Stage 1: Q GEMM (q_s overlay on V region, same-wave readback) -> barrier ->
//  fused K+V GEMM sharing x fragments.  K and V are stored FRAGMENT-MAJOR:
//  stage-2 reads are linear in lane = ZERO bank conflicts by construction.
//  Stage 2 (32 iters, zero barriers): TWO-DEEP SOFTWARE PIPELINE —
//    iter kb: issue loads for kb+64 (K frags + bias, wrapped);
//             compute S(kb+32) from regs loaded last iter  (no DS wait);
//             exp/pack S(kb) computed last iter; PV-MFMA with V(kb)
//             (V loaded this iter -- the exp block provides the slack).
//  The S->exp dependency now spans a full iteration, so the per-iter serial
//  chain (S-MFMA latency + 16 exp2 + pack + PV) overlaps across iterations
//  even at 4 waves/SIMD.  Same arithmetic, bit-identical output vs R1.
// ---------------------------------------------------------------------------
__global__ __launch_bounds__(1024, 4) void attn_kernel(
    const unsigned short* __restrict__ xt16,  // (b,n,c) bf16
    const unsigned short* __restrict__ w16,   // wq|wk|wv|wo (wk pre-scaled)
    const float* __restrict__ rel_bias,       // (h, 3969)
    unsigned short* __restrict__ ao16)        // (b, n, 256)
{
    __shared__ __align__(16) unsigned char smem[65536 + 65536 + BSTR * 4 * 4];
    unsigned short* k_s   = (unsigned short*)smem;             // 64 frags x 512 shorts
    unsigned short* v_s   = (unsigned short*)(smem + 65536);   // 64 frags x 512 shorts
    unsigned short* q_s   = (unsigned short*)(smem + 65536);   // overlay (512 x 32)
    float*          bias4 = (float*)(smem + 131072);           // [4][BSTR]

    const int id   = blockIdx.x;                    // 0..255
    const int bh_i = (id & 7) * 16 + (id >> 4);     // XCD x owns bh [16x,16x+16)
    const int half = (id >> 3) & 1;
    const int b = bh_i >> 3, h = bh_i & 7;

    const int t = threadIdx.x, wid = t >> 6, lane = t & 63;
    const int g = lane >> 4, ln = lane & 15;
    const int qb = half * 512 + wid * 32;           // wave's 32 queries

    const unsigned short* xb  = xt16 + (size_t)b * NTOK * CDIM;
    const unsigned short* wqh = w16 + (size_t)(h * 32) * CDIM;
    const unsigned short* wkh = w16 + 65536 + (size_t)(h * 32) * CDIM;
    const unsigned short* wvh = w16 + 2 * 65536 + (size_t)(h * 32) * CDIM;

    // ---- bias*log2e -> 4 shift-aligned copies, trimmed to this block's range ----
    {
        const int START = 544 - 512 * half;         // 4-aligned window base
        const float* brow = rel_bias + (size_t)h * 3969;
        for (int i = t; i < 1540; i += 1024) {
            #pragma unroll
            for (int a = 0; a < 4; ++a)
                bias4[a * BSTR + i] = brow[START + a + i] * L2E;
        }
    }

    // ---- Stage 1a: Q GEMM — rows [qb,+32); write+read via q_s (same wave) ----
    bf16x8 aq0, aq1;
    {
        f32x4 acc[2][2];
        #pragma unroll
        for (int m = 0; m < 2; ++m)
            #pragma unroll
            for (int n = 0; n < 2; ++n) acc[m][n] = (f32x4){0.f, 0.f, 0.f, 0.f};
        #pragma unroll
        for (int kt = 0; kt < CDIM; kt += 32) {
            bf16x8 a[2], w2[2];
            #pragma unroll
            for (int m = 0; m < 2; ++m)
                a[m] = *(const bf16x8*)&xb[(size_t)(qb + m * 16 + ln) * CDIM + kt + g * 8];
            #pragma unroll
            for (int n = 0; n < 2; ++n)
                w2[n] = *(const bf16x8*)&wqh[(size_t)(n * 16 + ln) * CDIM + kt + g * 8];
            #pragma unroll
            for (int m = 0; m < 2; ++m)
                #pragma unroll
                for (int n = 0; n < 2; ++n)
                    acc[m][n] = __builtin_amdgcn_mfma_f32_16x16x32_bf16(a[m], w2[n], acc[m][n], 0, 0, 0);
        }
        const int lr = wid * 32;
        #pragma unroll
        for (int m = 0; m < 2; ++m)
            #pragma unroll
            for (int n = 0; n < 2; ++n)
                #pragma unroll
                for (int r = 0; r < 4; ++r)
                    q_s[(size_t)(lr + m * 16 + g * 4 + r) * HDIM + n * 16 + ln] = f2bf(acc[m][n][r]);
        aq0 = *(const bf16x8*)&q_s[(size_t)(lr + ln) * HDIM + g * 8];
        aq1 = *(const bf16x8*)&q_s[(size_t)(lr + 16 + ln) * HDIM + g * 8];
    }

    __syncthreads();   // all q_s reads done before V overwrites the region

    // ---- Stage 1b: fused K+V GEMM — shared x fragments, tokens [wid*64,+64) ----
    {
        const int tr = wid * 64;
        f32x4 ak[4][2], av[2][4];
        #pragma unroll
        for (int m = 0; m < 4; ++m)
            #pragma unroll
            for (int n = 0; n < 2; ++n) {
                ak[m][n] = (f32x4){0.f, 0.f, 0.f, 0.f};
                av[n][m] = (f32x4){0.f, 0.f, 0.f, 0.f};
            }
        #pragma unroll
        for (int kt = 0; kt < CDIM; kt += 32) {
            bf16x8 xf[4], wkf[2], wvf[2];
            #pragma unroll
            for (int m = 0; m < 4; ++m)
                xf[m] = *(const bf16x8*)&xb[(size_t)(tr + m * 16 + ln) * CDIM + kt + g * 8];
            #pragma unroll
            for (int n = 0; n < 2; ++n) {
                wkf[n] = *(const bf16x8*)&wkh[(size_t)(n * 16 + ln) * CDIM + kt + g * 8];
                wvf[n] = *(const bf16x8*)&wvh[(size_t)(n * 16 + ln) * CDIM + kt + g * 8];
            }
            #pragma unroll
            for (int m = 0; m < 4; ++m) {
                ak[m][0] = __builtin_amdgcn_mfma_f32_16x16x32_bf16(xf[m], wkf[0], ak[m][0], 0, 0, 0);
                ak[m][1] = __builtin_amdgcn_mfma_f32_16x16x32_bf16(xf[m], wkf[1], ak[m][1], 0, 0, 0);
                av[0][m] = __builtin_amdgcn_mfma_f32_16x16x32_bf16(wvf[0], xf[m], av[0][m], 0, 0, 0);
                av[1][m] = __builtin_amdgcn_mfma_f32_16x16x32_bf16(wvf[1], xf[m], av[1][m], 0, 0, 0);
            }
        }
        // K store, fragment-major.  ak[m][n][r] = K[row=tr+m*16+g*4+r][col=n*16+ln].
        #pragma unroll
        for (int m = 0; m < 4; ++m) {
            const int fbase = (2 * wid + (m >> 1)) * 2 + (g & 1);
            #pragma unroll
            for (int n = 0; n < 2; ++n) {
                const int lhi = (2 * n + (ln >> 3)) * 16 + ((m & 1) * 2 + (g >> 1)) * 4;
                #pragma unroll
                for (int r = 0; r < 4; ++r)
                    k_s[fbase * 512 + (lhi + r) * 8 + (ln & 7)] = f2bf(ak[m][n][r]);
            }
        }
        // V store, fragment-major.  av[n][m][r] = V[d=n*16+g*4+r][tok=tr+m*16+ln].
        #pragma unroll
        for (int n = 0; n < 2; ++n)
            #pragma unroll
            for (int m = 0; m < 4; ++m) {
                const int fr  = (2 * wid + (m >> 1)) * 2 + n;
                const int lnb = ((m & 1) * 2 + (ln >> 3)) * 16 + g * 4;
                #pragma unroll
                for (int r = 0; r < 4; ++r)
                    v_s[fr * 512 + (lnb + r) * 8 + (ln & 7)] = f2bf(av[n][m][r]);
            }
    }

    __syncthreads();   // K, V, bias all LDS-resident

    // ---- Stage 2: attention main loop, 2-deep pipelined ----
    const int boffL = 512 + 8 * g - wid * 32 - ln;   // local bias offset
    const int ba = boffL & 3;
    const float* bb = &bias4[ba * BSTR + (boffL - ba)];
    const unsigned short* kfp = k_s + lane * 8;      // frag stride 512 shorts
    const unsigned short* vfp = v_s + lane * 8;

    f32x4 o00 = {0.f,0.f,0.f,0.f}, o01 = {0.f,0.f,0.f,0.f};
    f32x4 o10 = {0.f,0.f,0.f,0.f}, o11 = {0.f,0.f,0.f,0.f};
    f32x4 ls0 = {0.f,0.f,0.f,0.f}, ls1 = {0.f,0.f,0.f,0.f};
    const short one_bf = (short)0x3F80;
    const bf16x8 ones = {one_bf,one_bf,one_bf,one_bf,one_bf,one_bf,one_bf,one_bf};

    // prologue: K(0)+bias(0) -> S(0);  K(32)+bias(32) into regs for iter 0
    f32x4 s00, s01, s10, s11;
    {
        const bf16x8 k0 = *(const bf16x8*)&kfp[0];
        const bf16x8 k1 = *(const bf16x8*)&kfp[512];
        const f32x4  c0 = *(const f32x4*)&bb[0];
        const f32x4  c1 = *(const f32x4*)&bb[4];
        const f32x4  c2 = *(const f32x4*)&bb[-16];
        const f32x4  c3 = *(const f32x4*)&bb[-12];
        s00 = __builtin_amdgcn_mfma_f32_16x16x32_bf16(k0, aq0, c0, 0, 0, 0);
        s01 = __builtin_amdgcn_mfma_f32_16x16x32_bf16(k1, aq0, c1, 0, 0, 0);
        s10 = __builtin_amdgcn_mfma_f32_16x16x32_bf16(k0, aq1, c2, 0, 0, 0);
        s11 = __builtin_amdgcn_mfma_f32_16x16x32_bf16(k1, aq1, c3, 0, 0, 0);
    }
    bf16x8 kB0 = *(const bf16x8*)&kfp[2 * 512];   // K frags for kb=32
    bf16x8 kB1 = *(const bf16x8*)&kfp[3 * 512];
    f32x4  bA0 = *(const f32x4*)&bb[32];          // bias for kb=32
    f32x4  bA1 = *(const f32x4*)&bb[36];
    f32x4  bB0 = *(const f32x4*)&bb[16];
    f32x4  bB1 = *(const f32x4*)&bb[20];

    for (int kb = 0; kb < NTOK; kb += 32) {
        // issue loads for kb+64 (wrapped; dead for the last two iterations)
        const int kn = (kb + 64) & (NTOK - 1);
        const int fn = (kn >> 5) * 2;
        const bf16x8 nk0 = *(const bf16x8*)&kfp[fn * 512];
        const bf16x8 nk1 = *(const bf16x8*)&kfp[(fn + 1) * 512];
        const f32x4  nA0 = *(const f32x4*)&bb[kn];
        const f32x4  nA1 = *(const f32x4*)&bb[kn + 4];
        const f32x4  nB0 = *(const f32x4*)&bb[kn - 16];
        const f32x4  nB1 = *(const f32x4*)&bb[kn - 12];
        // V for THIS iter: consumed only after the exp/pack block -> slack.
        const int fi = (kb >> 5) * 2;
        const bf16x8 vA0 = *(const bf16x8*)&vfp[fi * 512];
        const bf16x8 vA1 = *(const bf16x8*)&vfp[(fi + 1) * 512];

        // S(kb+32) from registers loaded LAST iteration -- no DS wait.
        __builtin_amdgcn_s_setprio(1);
        const f32x4 t00 = __builtin_amdgcn_mfma_f32_16x16x32_bf16(kB0, aq0, bA0, 0, 0, 0);
        const f32x4 t01 = __builtin_amdgcn_mfma_f32_16x16x32_bf16(kB1, aq0, bA1, 0, 0, 0);
        const f32x4 t10 = __builtin_amdgcn_mfma_f32_16x16x32_bf16(kB0, aq1, bB0, 0, 0, 0);
        const f32x4 t11 = __builtin_amdgcn_mfma_f32_16x16x32_bf16(kB1, aq1, bB1, 0, 0, 0);
        __builtin_amdgcn_s_setprio(0);

        // exp/pack S(kb) computed LAST iteration (prologue for kb=0).
        // Pack P: shorts [e(s0[0..3]) | e(s1[0..3])] = keys kb+8g+0..7 in order.
        union { unsigned u4[4]; bf16x8 v; } ap0, ap1;
        ap0.u4[0] = cvt_pk_bf16(__builtin_amdgcn_exp2f(s00[0]), __builtin_amdgcn_exp2f(s00[1]));
        ap0.u4[1] = cvt_pk_bf16(__builtin_amdgcn_exp2f(s00[2]), __builtin_amdgcn_exp2f(s00[3]));
        ap0.u4[2] = cvt_pk_bf16(__builtin_amdgcn_exp2f(s01[0]), __builtin_amdgcn_exp2f(s01[1]));
        ap0.u4[3] = cvt_pk_bf16(__builtin_amdgcn_exp2f(s01[2]), __builtin_amdgcn_exp2f(s01[3]));
        ap1.u4[0] = cvt_pk_bf16(__builtin_amdgcn_exp2f(s10[0]), __builtin_amdgcn_exp2f(s10[1]));
        ap1.u4[1] = cvt_pk_bf16(__builtin_amdgcn_exp2f(s10[2]), __builtin_amdgcn_exp2f(s10[3]));
        ap1.u4[2] = cvt_pk_bf16(__builtin_amdgcn_exp2f(s11[0]), __builtin_amdgcn_exp2f(s11[1]));
        ap1.u4[3] = cvt_pk_bf16(__builtin_amdgcn_exp2f(s11[2]), __builtin_amdgcn_exp2f(s11[3]));

        __builtin_amdgcn_s_setprio(1);
        o00 = __builtin_amdgcn_mfma_f32_16x16x32_bf16(ap0.v, vA0, o00, 0, 0, 0);
        o01 = __builtin_amdgcn_mfma_f32_16x16x32_bf16(ap0.v, vA1, o01, 0, 0, 0);
        ls0 = __builtin_amdgcn_mfma_f32_16x16x32_bf16(ap0.v, ones, ls0, 0, 0, 0);
        o10 = __builtin_amdgcn_mfma_f32_16x16x32_bf16(ap1.v, vA0, o10, 0, 0, 0);
        o11 = __builtin_amdgcn_mfma_f32_16x16x32_bf16(ap1.v, vA1, o11, 0, 0, 0);
        ls1 = __builtin_amdgcn_mfma_f32_16x16x32_bf16(ap1.v, ones, ls1, 0, 0, 0);
        __builtin_amdgcn_s_setprio(0);

        // rotate pipeline registers
        s00 = t00; s01 = t01; s10 = t10; s11 = t11;
        kB0 = nk0; kB1 = nk1;
        bA0 = nA0; bA1 = nA1; bB0 = nB0; bB1 = nB1;
    }

    #pragma unroll
    for (int r = 0; r < 4; ++r) {
        float i0 = 1.f / ls0[r], i1 = 1.f / ls1[r];
        o00[r] *= i0; o01[r] *= i0;
        o10[r] *= i1; o11[r] *= i1;
    }

    __syncthreads();   // all waves done with k_s; overlay otr on K region
    unsigned short (*otr)[32][40] = (unsigned short(*)[32][40])smem;
    #pragma unroll
    for (int r = 0; r < 4; ++r) {
        otr[wid][g * 4 + r][ln]           = f2bf(o00[r]);
        otr[wid][g * 4 + r][16 + ln]      = f2bf(o01[r]);
        otr[wid][16 + g * 4 + r][ln]      = f2bf(o10[r]);
        otr[wid][16 + g * 4 + r][16 + ln] = f2bf(o11[r]);
    }
    // same-wave region: DS in-order, no barrier.  2 lanes/row x 16 d each.
    const int row = lane >> 1;
    const int ch  = (lane & 1) * 16;
    uint4 st0 = *(uint4*)&otr[wid][row][ch];
    uint4 st1 = *(uint4*)&otr[wid][row][ch + 8];
    unsigned short* dst = &ao16[((size_t)b * NTOK + qb + row) * CDIM + h * HDIM + ch];
    *(uint4*)dst     = st0;
    *(uint4*)&dst[8] = st1;
}

// ---------------------------------------------------------------------------
// Output projection: 64c x 128p per block, wave = 2 c-frags x 4 p-frags.
// XCD-swizzled flat grid 512.
// ---------------------------------------------------------------------------
__global__ __launch_bounds__(256) void outproj_kernel(
    const unsigned short* __restrict__ ao16,  // (b,n,256)
    const unsigned short* __restrict__ wo16,  // (256,256)
    const float* __restrict__ bo,
    float* __restrict__ y)                    // (b,256,n)
{
    const int id   = blockIdx.x;              // 0..511
    const int b    = (id & 7) * 2 + ((id >> 3) & 1);
    const int rest = id >> 4;                 // 0..31
    const int ct   = (rest & 3) * 64;
    const int pt   = (rest >> 2) * 128;
    const int t = threadIdx.x, wid = t >> 6, lane = t & 63;
    const int g = lane >> 4, ln = lane & 15;
    const int cb2 = ct + (wid & 1) * 32;
    const int pb  = pt + (wid >> 1) * 64;
    const unsigned short* ab = ao16 + (size_t)b * NTOK * CDIM;

    f32x4 acc[2][4];
    #pragma unroll
    for (int n = 0; n < 2; ++n)
        #pragma unroll
        for (int m = 0; m < 4; ++m) acc[n][m] = (f32x4){0.f, 0.f, 0.f, 0.f};

    #pragma unroll
    for (int kt = 0; kt < CDIM; kt += 32) {
        bf16x8 aw[2], bx[4];
        #pragma unroll
        for (int n = 0; n < 2; ++n)
            aw[n] = *(const bf16x8*)&wo16[(size_t)(cb2 + n * 16 + ln) * CDIM + kt + g * 8];
        #pragma unroll
        for (int m = 0; m < 4; ++m)
            bx[m] = *(const bf16x8*)&ab[(size_t)(pb + m * 16 + ln) * CDIM + kt + g * 8];
        #pragma unroll
        for (int n = 0; n < 2; ++n)
            #pragma unroll
            for (int m = 0; m < 4; ++m)
                acc[n][m] = __builtin_amdgcn_mfma_f32_16x16x32_bf16(aw[n], bx[m], acc[n][m], 0, 0, 0);
    }
    #pragma unroll
    for (int n = 0; n < 2; ++n)
        #pragma unroll
        for (int r = 0; r < 4; ++r) {
            const int c = cb2 + n * 16 + g * 4 + r;
            const float bias = bo[c];
            #pragma unroll
            for (int m = 0; m < 4; ++m)
                y[((size_t)b * CDIM + c) * NTOK + pb + m * 16 + ln] = acc[n][m][r] + bias;
        }
}

// ---------------------------------------------------------------------------
extern "C" void kernel_launch(void* const* d_in, const int* in_sizes, int n_in,
                              void* d_out, int out_size, void* d_ws, size_t ws_size,
                              hipStream_t stream) {
    const float* x        = (const float*)d_in[0];
    const float* Wq       = (const float*)d_in[1];
    const float* Wk       = (const float*)d_in[2];
    const float* Wv       = (const float*)d_in[3];
    const float* Wo       = (const float*)d_in[4];
    const float* bo       = (const float*)d_in[5];
    const float* rel_bias = (const float*)d_in[6];
    (void)in_sizes; (void)n_in; (void)ws_size; (void)out_size;
    // d_in[7] = rel_idx: unused — bias index computed analytically (j - p + 1056)

    unsigned short* ws16 = (unsigned short*)d_ws;
    unsigned short* xt16 = ws16;                              // 8 MB
    unsigned short* ao16 = ws16 + (size_t)4 * 1024 * 1024;    // 8 MB
    unsigned short* w16  = ws16 + (size_t)8 * 1024 * 1024;    // 512 KB
    float* y = (float*)d_out;

    prep_kernel<<<dim3(16, 4, 17), 256, 0, stream>>>(x, Wq, Wk, Wv, Wo, w16, xt16);
    attn_kernel<<<256, 1024, 0, stream>>>(xt16, w16, rel_bias, ao16);
    outproj_kernel<<<512, 256, 0, stream>>>(ao16, w16 + 3 * 65536, bo, y);
}

// Round 5
// 179.023 us; speedup vs baseline: 1.4609x; 1.0891x over previous
//
#include <hip/hip_runtime.h>

#define HEADS 8
#define HDIM 32
#define NTOK 1024
#define CDIM 256
#define BATCH 16
#define ATT_SCALE 0.17677669529663687f  // 32^-0.5
#define L2E 1.4426950408889634f
#define BSTR 1544   // bias copy stride (floats): 16B-aligned; 1544%32=8 -> ~2-way reads

typedef __attribute__((ext_vector_type(8))) short bf16x8;   // 8 bf16, 4 VGPRs
typedef __attribute__((ext_vector_type(4))) float f32x4;    // MFMA C/D

__device__ __forceinline__ unsigned short f2bf(float f) {
    unsigned int u = __float_as_uint(f);
    return (unsigned short)((u + 0x7fffu + ((u >> 16) & 1u)) >> 16);  // RNE
}

// pack two f32 -> (bf16(lo) | bf16(hi)<<16) in one instruction (no builtin on gfx950)
__device__ __forceinline__ unsigned cvt_pk_bf16(float lo, float hi) {
    unsigned r;
    asm("v_cvt_pk_bf16_f32 %0, %1, %2" : "=v"(r) : "v"(lo), "v"(hi));
    return r;
}

// ---------------------------------------------------------------------------
// Prep (fused): z<16 -> x (b,c,n) fp32 -> xt16 (b,n,c) bf16;  z==16 -> weights
// fp32 -> bf16.  Wk pre-scaled by ATT_SCALE*log2(e): S-MFMA output lands in
// log2 domain; bias (also *log2e) rides in the MFMA C operand; exp = v_exp_f32.
// ---------------------------------------------------------------------------
__global__ __launch_bounds__(256) void prep_kernel(
    const float* __restrict__ x,
    const float* __restrict__ Wq, const float* __restrict__ Wk,
    const float* __restrict__ Wv, const float* __restrict__ Wo,
    unsigned short* __restrict__ w16, unsigned short* __restrict__ xt16)
{
    const int t = threadIdx.x;
    if (blockIdx.z == 16) {
        const int which = blockIdx.y;
        const float* src = (which == 0) ? Wq : ((which == 1) ? Wk : ((which == 2) ? Wv : Wo));
        const float scale = (which == 1) ? (ATT_SCALE * L2E) : 1.0f;
        const int base = (blockIdx.x * 256 + t) * 16;
        #pragma unroll
        for (int i = 0; i < 4; ++i) {
            const int idx = base + i * 4;
            float4 v = *(const float4*)&src[idx];
            union { unsigned short h[4]; uint2 u; } pk;
            pk.h[0] = f2bf(v.x * scale); pk.h[1] = f2bf(v.y * scale);
            pk.h[2] = f2bf(v.z * scale); pk.h[3] = f2bf(v.w * scale);
            *(uint2*)&w16[(size_t)which * 65536 + idx] = pk.u;
        }
        return;
    }
    __shared__ float tile[64][65];
    const int b = blockIdx.z, ct = blockIdx.y * 64, nt = blockIdx.x * 64;
    const float* xb = x + ((size_t)b * CDIM + ct) * NTOK + nt;
    const int cc = t >> 4, n4 = (t & 15) * 4;
    #pragma unroll
    for (int i = 0; i < 4; ++i) {
        float4 v = *(const float4*)&xb[(size_t)(cc + 16 * i) * NTOK + n4];
        tile[cc + 16 * i][n4]     = v.x;
        tile[cc + 16 * i][n4 + 1] = v.y;
        tile[cc + 16 * i][n4 + 2] = v.z;
        tile[cc + 16 * i][n4 + 3] = v.w;
    }
    __syncthreads();
    const int c0 = (t & 7) * 8;          // 8 c-values per 16B store
    #pragma unroll
    for (int i = 0; i < 2; ++i) {
        const int nl = (t >> 3) + 32 * i;
        union { unsigned short h[8]; uint4 u; } pk;
        #pragma unroll
        for (int j = 0; j < 8; ++j) pk.h[j] = f2bf(tile[c0 + j][nl]);
        *(uint4*)&xt16[((size_t)b * NTOK + nt + nl) * CDIM + ct + c0] = pk.u;
    }
}

// ---------------------------------------------------------------------------
// Fused QKV + flash attention.  Block = (b, h, query-half): 1024 thr/16 waves.
//  Stage 1: Q GEMM (q_s overlay on V region, same-wave readback) -> barrier ->
//  K GEMM pass then V GEMM pass (SPLIT, 32 acc regs each, reusing the same
//  slots -- frees 32 unified-file registers for the stage-2 pipeline; the
//  fused version's 64 accumulators left zero headroom and R4's pipeline
//  spilled to scratch).  K and V stored FRAGMENT-MAJOR: stage-2 reads are
//  linear in lane = zero bank conflicts by construction.
//  Stage 2 (32 iters, zero barriers): MINIMAL-STATE PIPELINE — carry only S
//  (16 regs) across the back-edge:
//    iter kb: issue K/bias loads for kb+32;
//             exp/pack S(kb) computed LAST iter (covers the load latency);
//             S-MFMA(kb+32) from the just-loaded frags;
//             PV(kb) with V loaded this iter.
//  The S->exp->pack->PV chain spans a full iteration; no same-iteration DS
//  wait feeds the S-MFMAs.  Same arithmetic, bit-identical output.
// ---------------------------------------------------------------------------
__global__ __launch_bounds__(1024, 4) void attn_kernel(
    const unsigned short* __restrict__ xt16,  // (b,n,c) bf16
    const unsigned short* __restrict__ w16,   // wq|wk|wv|wo (wk pre-scaled)
    const float* __restrict__ rel_bias,       // (h, 3969)
    unsigned short* __restrict__ ao16)        // (b, n, 256)
{
    __shared__ __align__(16) unsigned char smem[65536 + 65536 + BSTR * 4 * 4];
    unsigned short* k_s   = (unsigned short*)smem;             // 64 frags x 512 shorts
    unsigned short* v_s   = (unsigned short*)(smem + 65536);   // 64 frags x 512 shorts
    unsigned short* q_s   = (unsigned short*)(smem + 65536);   // overlay (512 x 32)
    float*          bias4 = (float*)(smem + 131072);           // [4][BSTR]

    const int id   = blockIdx.x;                    // 0..255
    const int bh_i = (id & 7) * 16 + (id >> 4);     // XCD x owns bh [16x,16x+16)
    const int half = (id >> 3) & 1;
    const int b = bh_i >> 3, h = bh_i & 7;

    const int t = threadIdx.x, wid = t >> 6, lane = t & 63;
    const int g = lane >> 4, ln = lane & 15;
    const int qb = half * 512 + wid * 32;           // wave's 32 queries

    const unsigned short* xb  = xt16 + (size_t)b * NTOK * CDIM;
    const unsigned short* wqh = w16 + (size_t)(h * 32) * CDIM;
    const unsigned short* wkh = w16 + 65536 + (size_t)(h * 32) * CDIM;
    const unsigned short* wvh = w16 + 2 * 65536 + (size_t)(h * 32) * CDIM;

    // ---- bias*log2e -> 4 shift-aligned copies, trimmed to this block's range ----
    {
        const int START = 544 - 512 * half;         // 4-aligned window base
        const float* brow = rel_bias + (size_t)h * 3969;
        for (int i = t; i < 1540; i += 1024) {
            #pragma unroll
            for (int a = 0; a < 4; ++a)
                bias4[a * BSTR + i] = brow[START + a + i] * L2E;
        }
    }

    // ---- Stage 1a: Q GEMM — rows [qb,+32); write+read via q_s (same wave) ----
    bf16x8 aq0, aq1;
    {
        f32x4 acc[2][2];
        #pragma unroll
        for (int m = 0; m < 2; ++m)
            #pragma unroll
            for (int n = 0; n < 2; ++n) acc[m][n] = (f32x4){0.f, 0.f, 0.f, 0.f};
        #pragma unroll
        for (int kt = 0; kt < CDIM; kt += 32) {
            bf16x8 a[2], w2[2];
            #pragma unroll
            for (int m = 0; m < 2; ++m)
                a[m] = *(const bf16x8*)&xb[(size_t)(qb + m * 16 + ln) * CDIM + kt + g * 8];
            #pragma unroll
            for (int n = 0; n < 2; ++n)
                w2[n] = *(const bf16x8*)&wqh[(size_t)(n * 16 + ln) * CDIM + kt + g * 8];
            #pragma unroll
            for (int m = 0; m < 2; ++m)
                #pragma unroll
                for (int n = 0; n < 2; ++n)
                    acc[m][n] = __builtin_amdgcn_mfma_f32_16x16x32_bf16(a[m], w2[n], acc[m][n], 0, 0, 0);
        }
        const int lr = wid * 32;
        #pragma unroll
        for (int m = 0; m < 2; ++m)
            #pragma unroll
            for (int n = 0; n < 2; ++n)
                #pragma unroll
                for (int r = 0; r < 4; ++r)
                    q_s[(size_t)(lr + m * 16 + g * 4 + r) * HDIM + n * 16 + ln] = f2bf(acc[m][n][r]);
        aq0 = *(const bf16x8*)&q_s[(size_t)(lr + ln) * HDIM + g * 8];
        aq1 = *(const bf16x8*)&q_s[(size_t)(lr + 16 + ln) * HDIM + g * 8];
    }

    __syncthreads();   // all q_s reads done before V overwrites the region

    // ---- Stage 1b-K: K GEMM — tokens [wid*64,+64), 32 acc regs ----
    {
        const int tr = wid * 64;
        f32x4 ak[4][2];
        #pragma unroll
        for (int m = 0; m < 4; ++m)
            #pragma unroll
            for (int n = 0; n < 2; ++n) ak[m][n] = (f32x4){0.f, 0.f, 0.f, 0.f};
        #pragma unroll
        for (int kt = 0; kt < CDIM; kt += 32) {
            bf16x8 xf[4], wkf[2];
            #pragma unroll
            for (int m = 0; m < 4; ++m)
                xf[m] = *(const bf16x8*)&xb[(size_t)(tr + m * 16 + ln) * CDIM + kt + g * 8];
            #pragma unroll
            for (int n = 0; n < 2; ++n)
                wkf[n] = *(const bf16x8*)&wkh[(size_t)(n * 16 + ln) * CDIM + kt + g * 8];
            #pragma unroll
            for (int m = 0; m < 4; ++m) {
                ak[m][0] = __builtin_amdgcn_mfma_f32_16x16x32_bf16(xf[m], wkf[0], ak[m][0], 0, 0, 0);
                ak[m][1] = __builtin_amdgcn_mfma_f32_16x16x32_bf16(xf[m], wkf[1], ak[m][1], 0, 0, 0);
            }
        }
        // K store, fragment-major.  ak[m][n][r] = K[row=tr+m*16+g*4+r][col=n*16+ln].
        #pragma unroll
        for (int m = 0; m < 4; ++m) {
            const int fbase = (2 * wid + (m >> 1)) * 2 + (g & 1);
            #pragma unroll
            for (int n = 0; n < 2; ++n) {
                const int lhi = (2 * n + (ln >> 3)) * 16 + ((m & 1) * 2 + (g >> 1)) * 4;
                #pragma unroll
                for (int r = 0; r < 4; ++r)
                    k_s[fbase * 512 + (lhi + r) * 8 + (ln & 7)] = f2bf(ak[m][n][r]);
            }
        }
    }
    asm volatile("" ::: "memory");   // fence: keep V pass from CSE/overlapping K pass regs

    // ---- Stage 1b-V: V GEMM — same tokens, reusing the 32 acc slots ----
    {
        const int tr = wid * 64;
        f32x4 av[2][4];
        #pragma unroll
        for (int n = 0; n < 2; ++n)
            #pragma unroll
            for (int m = 0; m < 4; ++m) av[n][m] = (f32x4){0.f, 0.f, 0.f, 0.f};
        #pragma unroll
        for (int kt = 0; kt < CDIM; kt += 32) {
            bf16x8 xf[4], wvf[2];
            #pragma unroll
            for (int m = 0; m < 4; ++m)
                xf[m] = *(const bf16x8*)&xb[(size_t)(tr + m * 16 + ln) * CDIM + kt + g * 8];
            #pragma unroll
            for (int n = 0; n < 2; ++n)
                wvf[n] = *(const bf16x8*)&wvh[(size_t)(n * 16 + ln) * CDIM + kt + g * 8];
            #pragma unroll
            for (int m = 0; m < 4; ++m) {
                av[0][m] = __builtin_amdgcn_mfma_f32_16x16x32_bf16(wvf[0], xf[m], av[0][m], 0, 0, 0);
                av[1][m] = __builtin_amdgcn_mfma_f32_16x16x32_bf16(wvf[1], xf[m], av[1][m], 0, 0, 0);
            }
        }
        // V store, fragment-major.  av[n][m][r] = V[d=n*16+g*4+r][tok=tr+m*16+ln].
        #pragma unroll
        for (int n = 0; n < 2; ++n)
            #pragma unroll
            for (int m = 0; m < 4; ++m) {
                const int fr  = (2 * wid + (m >> 1)) * 2 + n;
                const int lnb = ((m & 1) * 2 + (ln >> 3)) * 16 + g * 4;
                #pragma unroll
                for (int r = 0; r < 4; ++r)
                    v_s[fr * 512 + (lnb + r) * 8 + (ln & 7)] = f2bf(av[n][m][r]);
            }
    }

    __syncthreads();   // K, V, bias all LDS-resident

    // ---- Stage 2: attention main loop, S-carried pipeline ----
    const int boffL = 512 + 8 * g - wid * 32 - ln;   // local bias offset
    const int ba = boffL & 3;
    const float* bb = &bias4[ba * BSTR + (boffL - ba)];
    const unsigned short* kfp = k_s + lane * 8;      // frag stride 512 shorts
    const unsigned short* vfp = v_s + lane * 8;

    f32x4 o00 = {0.f,0.f,0.f,0.f}, o01 = {0.f,0.f,0.f,0.f};
    f32x4 o10 = {0.f,0.f,0.f,0.f}, o11 = {0.f,0.f,0.f,0.f};
    f32x4 ls0 = {0.f,0.f,0.f,0.f}, ls1 = {0.f,0.f,0.f,0.f};
    const short one_bf = (short)0x3F80;
    const bf16x8 ones = {one_bf,one_bf,one_bf,one_bf,one_bf,one_bf,one_bf,one_bf};

    // prologue: S(0) from K(0)/bias(0)
    f32x4 s00, s01, s10, s11;
    {
        const bf16x8 k0 = *(const bf16x8*)&kfp[0];
        const bf16x8 k1 = *(const bf16x8*)&kfp[512];
        const f32x4  c0 = *(const f32x4*)&bb[0];
        const f32x4  c1 = *(const f32x4*)&bb[4];
        const f32x4  c2 = *(const f32x4*)&bb[-16];
        const f32x4  c3 = *(const f32x4*)&bb[-12];
        s00 = __builtin_amdgcn_mfma_f32_16x16x32_bf16(k0, aq0, c0, 0, 0, 0);
        s01 = __builtin_amdgcn_mfma_f32_16x16x32_bf16(k1, aq0, c1, 0, 0, 0);
        s10 = __builtin_amdgcn_mfma_f32_16x16x32_bf16(k0, aq1, c2, 0, 0, 0);
        s11 = __builtin_amdgcn_mfma_f32_16x16x32_bf16(k1, aq1, c3, 0, 0, 0);
    }

    for (int kb = 0; kb < NTOK; kb += 32) {
        // issue loads for S(kb+32): K frags + bias (wrapped; dead on last iter)
        const int kn = (kb + 32) & (NTOK - 1);
        const int fn = (kn >> 5) * 2;
        const bf16x8 kf0 = *(const bf16x8*)&kfp[fn * 512];
        const bf16x8 kf1 = *(const bf16x8*)&kfp[(fn + 1) * 512];
        const f32x4  cA0 = *(const f32x4*)&bb[kn];
        const f32x4  cA1 = *(const f32x4*)&bb[kn + 4];
        const f32x4  cB0 = *(const f32x4*)&bb[kn - 16];
        const f32x4  cB1 = *(const f32x4*)&bb[kn - 12];
        // V for THIS iter: consumed at the very end -> maximal slack.
        const int fi = (kb >> 5) * 2;
        const bf16x8 vA0 = *(const bf16x8*)&vfp[fi * 512];
        const bf16x8 vA1 = *(const bf16x8*)&vfp[(fi + 1) * 512];

        // exp/pack S(kb) computed LAST iteration -- independent of the loads
        // above; its VALU/trans work covers their LDS latency.
        union { unsigned u4[4]; bf16x8 v; } ap0, ap1;
        ap0.u4[0] = cvt_pk_bf16(__builtin_amdgcn_exp2f(s00[0]), __builtin_amdgcn_exp2f(s00[1]));
        ap0.u4[1] = cvt_pk_bf16(__builtin_amdgcn_exp2f(s00[2]), __builtin_amdgcn_exp2f(s00[3]));
        ap0.u4[2] = cvt_pk_bf16(__builtin_amdgcn_exp2f(s01[0]), __builtin_amdgcn_exp2f(s01[1]));
        ap0.u4[3] = cvt_pk_bf16(__builtin_amdgcn_exp2f(s01[2]), __builtin_amdgcn_exp2f(s01[3]));
        ap1.u4[0] = cvt_pk_bf16(__builtin_amdgcn_exp2f(s10[0]), __builtin_amdgcn_exp2f(s10[1]));
        ap1.u4[1] = cvt_pk_bf16(__builtin_amdgcn_exp2f(s10[2]), __builtin_amdgcn_exp2f(s10[3]));
        ap1.u4[2] = cvt_pk_bf16(__builtin_amdgcn_exp2f(s11[0]), __builtin_amdgcn_exp2f(s11[1]));
        ap1.u4[3] = cvt_pk_bf16(__builtin_amdgcn_exp2f(s11[2]), __builtin_amdgcn_exp2f(s11[3]));

        // S(kb+32): loads above have ~the exp block of cover.
        __builtin_amdgcn_s_setprio(1);
        const f32x4 t00 = __builtin_amdgcn_mfma_f32_16x16x32_bf16(kf0, aq0, cA0, 0, 0, 0);
        const f32x4 t01 = __builtin_amdgcn_mfma_f32_16x16x32_bf16(kf1, aq0, cA1, 0, 0, 0);
        const f32x4 t10 = __builtin_amdgcn_mfma_f32_16x16x32_bf16(kf0, aq1, cB0, 0, 0, 0);
        const f32x4 t11 = __builtin_amdgcn_mfma_f32_16x16x32_bf16(kf1, aq1, cB1, 0, 0, 0);

        // PV(kb)
        o00 = __builtin_amdgcn_mfma_f32_16x16x32_bf16(ap0.v, vA0, o00, 0, 0, 0);
        o01 = __builtin_amdgcn_mfma_f32_16x16x32_bf16(ap0.v, vA1, o01, 0, 0, 0);
        ls0 = __builtin_amdgcn_mfma_f32_16x16x32_bf16(ap0.v, ones, ls0, 0, 0, 0);
        o10 = __builtin_amdgcn_mfma_f32_16x16x32_bf16(ap1.v, vA0, o10, 0, 0, 0);
        o11 = __builtin_amdgcn_mfma_f32_16x16x32_bf16(ap1.v, vA1, o11, 0, 0, 0);
        ls1 = __builtin_amdgcn_mfma_f32_16x16x32_bf16(ap1.v, ones, ls1, 0, 0, 0);
        __builtin_amdgcn_s_setprio(0);

        s00 = t00; s01 = t01; s10 = t10; s11 = t11;
    }

    #pragma unroll
    for (int r = 0; r < 4; ++r) {
        float i0 = 1.f / ls0[r], i1 = 1.f / ls1[r];
        o00[r] *= i0; o01[r] *= i0;
        o10[r] *= i1; o11[r] *= i1;
    }

    __syncthreads();   // all waves done with k_s; overlay otr on K region
    unsigned short (*otr)[32][40] = (unsigned short(*)[32][40])smem;
    #pragma unroll
    for (int r = 0; r < 4; ++r) {
        otr[wid][g * 4 + r][ln]           = f2bf(o00[r]);
        otr[wid][g * 4 + r][16 + ln]      = f2bf(o01[r]);
        otr[wid][16 + g * 4 + r][ln]      = f2bf(o10[r]);
        otr[wid][16 + g * 4 + r][16 + ln] = f2bf(o11[r]);
    }
    // same-wave region: DS in-order, no barrier.  2 lanes/row x 16 d each.
    const int row = lane >> 1;
    const int ch  = (lane & 1) * 16;
    uint4 st0 = *(uint4*)&otr[wid][row][ch];
    uint4 st1 = *(uint4*)&otr[wid][row][ch + 8];
    unsigned short* dst = &ao16[((size_t)b * NTOK + qb + row) * CDIM + h * HDIM + ch];
    *(uint4*)dst     = st0;
    *(uint4*)&dst[8] = st1;
}

// ---------------------------------------------------------------------------
// Output projection: 64c x 128p per block, wave = 2 c-frags x 4 p-frags.
// XCD-swizzled flat grid 512.
// ---------------------------------------------------------------------------
__global__ __launch_bounds__(256) void outproj_kernel(
    const unsigned short* __restrict__ ao16,  // (b,n,256)
    const unsigned short* __restrict__ wo16,  // (256,256)
    const float* __restrict__ bo,
    float* __restrict__ y)                    // (b,256,n)
{
    const int id   = blockIdx.x;              // 0..511
    const int b    = (id & 7) * 2 + ((id >> 3) & 1);
    const int rest = id >> 4;                 // 0..31
    const int ct   = (rest & 3) * 64;
    const int pt   = (rest >> 2) * 128;
    const int t = threadIdx.x, wid = t >> 6, lane = t & 63;
    const int g = lane >> 4, ln = lane & 15;
    const int cb2 = ct + (wid & 1) * 32;
    const int pb  = pt + (wid >> 1) * 64;
    const unsigned short* ab = ao16 + (size_t)b * NTOK * CDIM;

    f32x4 acc[2][4];
    #pragma unroll
    for (int n = 0; n < 2; ++n)
        #pragma unroll
        for (int m = 0; m < 4; ++m) acc[n][m] = (f32x4){0.f, 0.f, 0.f, 0.f};

    #pragma unroll
    for (int kt = 0; kt < CDIM; kt += 32) {
        bf16x8 aw[2], bx[4];
        #pragma unroll
        for (int n = 0; n < 2; ++n)
            aw[n] = *(const bf16x8*)&wo16[(size_t)(cb2 + n * 16 + ln) * CDIM + kt + g * 8];
        #pragma unroll
        for (int m = 0; m < 4; ++m)
            bx[m] = *(const bf16x8*)&ab[(size_t)(pb + m * 16 + ln) * CDIM + kt + g * 8];
        #pragma unroll
        for (int n = 0; n < 2; ++n)
            #pragma unroll
            for (int m = 0; m < 4; ++m)
                acc[n][m] = __builtin_amdgcn_mfma_f32_16x16x32_bf16(aw[n], bx[m], acc[n][m], 0, 0, 0);
    }
    #pragma unroll
    for (int n = 0; n < 2; ++n)
        #pragma unroll
        for (int r = 0; r < 4; ++r) {
            const int c = cb2 + n * 16 + g * 4 + r;
            const float bias = bo[c];
            #pragma unroll
            for (int m = 0; m < 4; ++m)
                y[((size_t)b * CDIM + c) * NTOK + pb + m * 16 + ln] = acc[n][m][r] + bias;
        }
}

// ---------------------------------------------------------------------------
extern "C" void kernel_launch(void* const* d_in, const int* in_sizes, int n_in,
                              void* d_out, int out_size, void* d_ws, size_t ws_size,
                              hipStream_t stream) {
    const float* x        = (const float*)d_in[0];
    const float* Wq       = (const float*)d_in[1];
    const float* Wk       = (const float*)d_in[2];
    const float* Wv       = (const float*)d_in[3];
    const float* Wo       = (const float*)d_in[4];
    const float* bo       = (const float*)d_in[5];
    const float* rel_bias = (const float*)d_in[6];
    (void)in_sizes; (void)n_in; (void)ws_size; (void)out_size;
    // d_in[7] = rel_idx: unused — bias index computed analytically (j - p + 1056)

    unsigned short* ws16 = (unsigned short*)d_ws;
    unsigned short* xt16 = ws16;                              // 8 MB
    unsigned short* ao16 = ws16 + (size_t)4 * 1024 * 1024;    // 8 MB
    unsigned short* w16  = ws16 + (size_t)8 * 1024 * 1024;    // 512 KB
    float* y = (float*)d_out;

    prep_kernel<<<dim3(16, 4, 17), 256, 0, stream>>>(x, Wq, Wk, Wv, Wo, w16, xt16);
    attn_kernel<<<256, 1024, 0, stream>>>(xt16, w16, rel_bias, ao16);
    outproj_kernel<<<512, 256, 0, stream>>>(ao16, w16 + 3 * 65536, bo, y);
}

// Round 6
// 157.992 us; speedup vs baseline: 1.6553x; 1.1331x over previous
//
#include <hip/hip_runtime.h>

#define HEADS 8
#define HDIM 32
#define NTOK 1024
#define CDIM 256
#define BATCH 16
#define ATT_SCALE 0.17677669529663687f  // 32^-0.5
#define L2E 1.4426950408889634f
#define BSTR 1544   // bias copy stride (floats): 16B-aligned; 1544%32=8 -> ~2-way reads

typedef __attribute__((ext_vector_type(8))) short bf16x8;   // 8 bf16, 4 VGPRs
typedef __attribute__((ext_vector_type(4))) float f32x4;    // MFMA C/D

__device__ __forceinline__ unsigned short f2bf(float f) {
    unsigned int u = __float_as_uint(f);
    return (unsigned short)((u + 0x7fffu + ((u >> 16) & 1u)) >> 16);  // RNE
}

// pack two f32 -> (bf16(lo) | bf16(hi)<<16) in one instruction (no builtin on gfx950)
__device__ __forceinline__ unsigned cvt_pk_bf16(float lo, float hi) {
    unsigned r;
    asm("v_cvt_pk_bf16_f32 %0, %1, %2" : "=v"(r) : "v"(lo), "v"(hi));
    return r;
}

// ---------------------------------------------------------------------------
// Prep (fused): z<16 -> x (b,c,n) fp32 -> xt16 (b,n,c) bf16;  z==16 -> weights
// fp32 -> bf16.  Wk pre-scaled by ATT_SCALE*log2(e): S-MFMA output lands in
// log2 domain; bias (also *log2e) rides in the MFMA C operand; exp = v_exp_f32.
// ---------------------------------------------------------------------------
__global__ __launch_bounds__(256) void prep_kernel(
    const float* __restrict__ x,
    const float* __restrict__ Wq, const float* __restrict__ Wk,
    const float* __restrict__ Wv, const float* __restrict__ Wo,
    unsigned short* __restrict__ w16, unsigned short* __restrict__ xt16)
{
    const int t = threadIdx.x;
    if (blockIdx.z == 16) {
        const int which = blockIdx.y;
        const float* src = (which == 0) ? Wq : ((which == 1) ? Wk : ((which == 2) ? Wv : Wo));
        const float scale = (which == 1) ? (ATT_SCALE * L2E) : 1.0f;
        const int base = (blockIdx.x * 256 + t) * 16;
        #pragma unroll
        for (int i = 0; i < 4; ++i) {
            const int idx = base + i * 4;
            float4 v = *(const float4*)&src[idx];
            union { unsigned short h[4]; uint2 u; } pk;
            pk.h[0] = f2bf(v.x * scale); pk.h[1] = f2bf(v.y * scale);
            pk.h[2] = f2bf(v.z * scale); pk.h[3] = f2bf(v.w * scale);
            *(uint2*)&w16[(size_t)which * 65536 + idx] = pk.u;
        }
        return;
    }
    __shared__ float tile[64][65];
    const int b = blockIdx.z, ct = blockIdx.y * 64, nt = blockIdx.x * 64;
    const float* xb = x + ((size_t)b * CDIM + ct) * NTOK + nt;
    const int cc = t >> 4, n4 = (t & 15) * 4;
    #pragma unroll
    for (int i = 0; i < 4; ++i) {
        float4 v = *(const float4*)&xb[(size_t)(cc + 16 * i) * NTOK + n4];
        tile[cc + 16 * i][n4]     = v.x;
        tile[cc + 16 * i][n4 + 1] = v.y;
        tile[cc + 16 * i][n4 + 2] = v.z;
        tile[cc + 16 * i][n4 + 3] = v.w;
    }
    __syncthreads();
    const int c0 = (t & 7) * 8;          // 8 c-values per 16B store
    #pragma unroll
    for (int i = 0; i < 2; ++i) {
        const int nl = (t >> 3) + 32 * i;
        union { unsigned short h[8]; uint4 u; } pk;
        #pragma unroll
        for (int j = 0; j < 8; ++j) pk.h[j] = f2bf(tile[c0 + j][nl]);
        *(uint4*)&xt16[((size_t)b * NTOK + nt + nl) * CDIM + ct + c0] = pk.u;
    }
}

// ---------------------------------------------------------------------------
// QKV GEMM: block = (b, h, token-half), 16 waves, 32 tokens/wave, NO LDS.
// One pass over x per 512 tokens computes Q, K, V sharing the x fragments
// (K/V computed ONCE per (b,h) -- the old in-attn version duplicated them
// per query-half; x traffic drops 192 MB -> 64 MB).  K/V are written to
// global in the FRAGMENT-MAJOR layout attn's LDS wants (linear lane copy);
// Q row-major.  Same per-kt MFMA order as before -> bit-identical values.
// id mapping matches attn's, so the (b,h) writer and both readers land on
// the same XCD (L2-local handoff).
// ---------------------------------------------------------------------------
__global__ __launch_bounds__(1024, 4) void qkv_kernel(
    const unsigned short* __restrict__ xt16,  // (b,n,c) bf16
    const unsigned short* __restrict__ w16,   // wq|wk|wv|wo (wk pre-scaled)
    unsigned short* __restrict__ q16,         // (b,n,h,32)
    unsigned short* __restrict__ k16,         // (b,h, 64 frag, 512)
    unsigned short* __restrict__ v16)         // (b,h, 64 frag, 512)
{
    const int id   = blockIdx.x;                    // 0..255
    const int bh_i = (id & 7) * 16 + (id >> 4);
    const int tokhalf = (id >> 3) & 1;
    const int b = bh_i >> 3, h = bh_i & 7;

    const int t = threadIdx.x, wid = t >> 6, lane = t & 63;
    const int g = lane >> 4, ln = lane & 15;
    const int tr = tokhalf * 512 + wid * 32;        // wave's 32 tokens

    const unsigned short* xb  = xt16 + (size_t)b * NTOK * CDIM;
    const unsigned short* wqh = w16 + (size_t)(h * 32) * CDIM;
    const unsigned short* wkh = w16 + 65536 + (size_t)(h * 32) * CDIM;
    const unsigned short* wvh = w16 + 2 * 65536 + (size_t)(h * 32) * CDIM;

    f32x4 aq[2][2], ak[2][2], av[2][2];
    #pragma unroll
    for (int m = 0; m < 2; ++m)
        #pragma unroll
        for (int n = 0; n < 2; ++n) {
            aq[m][n] = (f32x4){0.f, 0.f, 0.f, 0.f};
            ak[m][n] = (f32x4){0.f, 0.f, 0.f, 0.f};
            av[n][m] = (f32x4){0.f, 0.f, 0.f, 0.f};
        }
    #pragma unroll
    for (int kt = 0; kt < CDIM; kt += 32) {
        bf16x8 xf[2], wqf[2], wkf[2], wvf[2];
        #pragma unroll
        for (int m = 0; m < 2; ++m)
            xf[m] = *(const bf16x8*)&xb[(size_t)(tr + m * 16 + ln) * CDIM + kt + g * 8];
        #pragma unroll
        for (int n = 0; n < 2; ++n) {
            wqf[n] = *(const bf16x8*)&wqh[(size_t)(n * 16 + ln) * CDIM + kt + g * 8];
            wkf[n] = *(const bf16x8*)&wkh[(size_t)(n * 16 + ln) * CDIM + kt + g * 8];
            wvf[n] = *(const bf16x8*)&wvh[(size_t)(n * 16 + ln) * CDIM + kt + g * 8];
        }
        #pragma unroll
        for (int m = 0; m < 2; ++m)
            #pragma unroll
            for (int n = 0; n < 2; ++n) {
                aq[m][n] = __builtin_amdgcn_mfma_f32_16x16x32_bf16(xf[m], wqf[n], aq[m][n], 0, 0, 0);
                ak[m][n] = __builtin_amdgcn_mfma_f32_16x16x32_bf16(xf[m], wkf[n], ak[m][n], 0, 0, 0);
                av[n][m] = __builtin_amdgcn_mfma_f32_16x16x32_bf16(wvf[n], xf[m], av[n][m], 0, 0, 0);
            }
    }

    // Q store, row-major (b,n,h,32).  aq[m][n][r] = Q[row=tr+m*16+g*4+r][col=n*16+ln].
    #pragma unroll
    for (int m = 0; m < 2; ++m)
        #pragma unroll
        for (int n = 0; n < 2; ++n)
            #pragma unroll
            for (int r = 0; r < 4; ++r)
                q16[((size_t)(b * NTOK + tr + m * 16 + g * 4 + r) * 8 + h) * 32 + n * 16 + ln] =
                    f2bf(aq[m][n][r]);

    // K store, fragment-major (row>>5 has m>>1 == 0 here, f is m-independent).
    unsigned short* kb16 = k16 + (size_t)(b * 8 + h) * 32768;
    const int fK = (tokhalf * 16 + wid) * 2 + (g & 1);
    #pragma unroll
    for (int m = 0; m < 2; ++m)
        #pragma unroll
        for (int n = 0; n < 2; ++n) {
            const int lhi = (2 * n + (ln >> 3)) * 16 + (m * 2 + (g >> 1)) * 4;
            #pragma unroll
            for (int r = 0; r < 4; ++r)
                kb16[fK * 512 + (lhi + r) * 8 + (ln & 7)] = f2bf(ak[m][n][r]);
        }

    // V store, fragment-major.  av[n][m][r] = V[d=n*16+g*4+r][tok=tr+m*16+ln].
    unsigned short* vb16 = v16 + (size_t)(b * 8 + h) * 32768;
    #pragma unroll
    for (int n = 0; n < 2; ++n) {
        const int fV = (tokhalf * 16 + wid) * 2 + n;
        #pragma unroll
        for (int m = 0; m < 2; ++m) {
            const int lnb = (m * 2 + (ln >> 3)) * 16 + g * 4;
            #pragma unroll
            for (int r = 0; r < 4; ++r)
                vb16[fV * 512 + (lnb + r) * 8 + (ln & 7)] = f2bf(av[n][m][r]);
        }
    }
}

// ---------------------------------------------------------------------------
// Flash attention.  Block = (b, h, query-half): 1024 thr/16 waves.
// QKV precomputed: stage K/V frags global->reg->LDS (linear lane copy, zero
// bank conflicts), 2 Q fragment loads, bias4 build -- all overlapped by the
// compiler -- then ONE barrier and the proven R1 stage-2 loop (K+bias
// prefetched 1 iter ahead, cvt_pk packing, setprio on MFMA clusters).
// ---------------------------------------------------------------------------
__global__ __launch_bounds__(1024, 4) void attn_kernel(
    const unsigned short* __restrict__ q16,   // (b,n,h,32)
    const unsigned short* __restrict__ k16,   // (b,h,64,512) frag-major
    const unsigned short* __restrict__ v16,   // (b,h,64,512) frag-major
    const float* __restrict__ rel_bias,       // (h, 3969)
    unsigned short* __restrict__ ao16)        // (b, n, 256)
{
    __shared__ __align__(16) unsigned char smem[65536 + 65536 + BSTR * 4 * 4];
    unsigned short* k_s   = (unsigned short*)smem;             // 64 frags x 512 shorts
    unsigned short* v_s   = (unsigned short*)(smem + 65536);   // 64 frags x 512 shorts
    float*          bias4 = (float*)(smem + 131072);           // [4][BSTR]

    const int id   = blockIdx.x;                    // 0..255
    const int bh_i = (id & 7) * 16 + (id >> 4);     // XCD x owns bh [16x,16x+16)
    const int half = (id >> 3) & 1;
    const int b = bh_i >> 3, h = bh_i & 7;

    const int t = threadIdx.x, wid = t >> 6, lane = t & 63;
    const int g = lane >> 4, ln = lane & 15;
    const int qb = half * 512 + wid * 32;           // wave's 32 queries

    const unsigned short* kbh = k16 + (size_t)(b * 8 + h) * 32768;
    const unsigned short* vbh = v16 + (size_t)(b * 8 + h) * 32768;

    // ---- stage K/V fragments: global -> reg (issue early) ----
    bf16x8 sk[4], sv[4];
    #pragma unroll
    for (int j = 0; j < 4; ++j) {
        const int f = wid * 4 + j;
        sk[j] = *(const bf16x8*)&kbh[(size_t)f * 512 + lane * 8];
        sv[j] = *(const bf16x8*)&vbh[(size_t)f * 512 + lane * 8];
    }
    // ---- Q fragments ----
    const bf16x8 aq0 = *(const bf16x8*)&q16[((size_t)(b * NTOK + qb + ln) * 8 + h) * 32 + g * 8];
    const bf16x8 aq1 = *(const bf16x8*)&q16[((size_t)(b * NTOK + qb + 16 + ln) * 8 + h) * 32 + g * 8];

    // ---- bias*log2e -> 4 shift-aligned copies (overlaps the loads above) ----
    {
        const int START = 544 - 512 * half;         // 4-aligned window base
        const float* brow = rel_bias + (size_t)h * 3969;
        for (int i = t; i < 1540; i += 1024) {
            #pragma unroll
            for (int a = 0; a < 4; ++a)
                bias4[a * BSTR + i] = brow[START + a + i] * L2E;
        }
    }

    // ---- commit staged frags to LDS (linear in lane = conflict-free) ----
    #pragma unroll
    for (int j = 0; j < 4; ++j) {
        const int f = wid * 4 + j;
        *(bf16x8*)&k_s[(size_t)f * 512 + lane * 8] = sk[j];
        *(bf16x8*)&v_s[(size_t)f * 512 + lane * 8] = sv[j];
    }

    __syncthreads();   // K, V, bias all LDS-resident

    // ---- Stage 2: attention main loop (R1 schedule, verbatim) ----
    const int boffL = 512 + 8 * g - wid * 32 - ln;   // local bias offset
    const int ba = boffL & 3;
    const float* bb = &bias4[ba * BSTR + (boffL - ba)];
    const unsigned short* kfp = k_s + lane * 8;      // frag stride 512 shorts
    const unsigned short* vfp = v_s + lane * 8;

    f32x4 o00 = {0.f,0.f,0.f,0.f}, o01 = {0.f,0.f,0.f,0.f};
    f32x4 o10 = {0.f,0.f,0.f,0.f}, o11 = {0.f,0.f,0.f,0.f};
    f32x4 ls0 = {0.f,0.f,0.f,0.f}, ls1 = {0.f,0.f,0.f,0.f};
    const short one_bf = (short)0x3F80;
    const bf16x8 ones = {one_bf,one_bf,one_bf,one_bf,one_bf,one_bf,one_bf,one_bf};

    // prologue: iter-0 K fragments + bias C-operands
    bf16x8 kf0 = *(const bf16x8*)&kfp[0];
    bf16x8 kf1 = *(const bf16x8*)&kfp[512];
    f32x4  cA0 = *(const f32x4*)&bb[0];
    f32x4  cA1 = *(const f32x4*)&bb[4];
    f32x4  cB0 = *(const f32x4*)&bb[-16];
    f32x4  cB1 = *(const f32x4*)&bb[-12];

    for (int kb = 0; kb < NTOK; kb += 32) {
        const int fi = (kb >> 5) * 2;
        // V for THIS iter: consumed only after S-MFMA + exp chain -> self-hiding.
        const bf16x8 vA0 = *(const bf16x8*)&vfp[fi * 512];
        const bf16x8 vA1 = *(const bf16x8*)&vfp[(fi + 1) * 512];
        // prefetch NEXT iter's K + bias (wrap keeps addresses in-bounds).
        const int kn = (kb + 32) & (NTOK - 1);
        const int fn = (kn >> 5) * 2;
        const bf16x8 nk0 = *(const bf16x8*)&kfp[fn * 512];
        const bf16x8 nk1 = *(const bf16x8*)&kfp[(fn + 1) * 512];
        const f32x4  nA0 = *(const f32x4*)&bb[kn];
        const f32x4  nA1 = *(const f32x4*)&bb[kn + 4];
        const f32x4  nB0 = *(const f32x4*)&bb[kn - 16];
        const f32x4  nB1 = *(const f32x4*)&bb[kn - 12];

        __builtin_amdgcn_s_setprio(1);
        f32x4 s00 = __builtin_amdgcn_mfma_f32_16x16x32_bf16(kf0, aq0, cA0, 0, 0, 0);
        f32x4 s01 = __builtin_amdgcn_mfma_f32_16x16x32_bf16(kf1, aq0, cA1, 0, 0, 0);
        f32x4 s10 = __builtin_amdgcn_mfma_f32_16x16x32_bf16(kf0, aq1, cB0, 0, 0, 0);
        f32x4 s11 = __builtin_amdgcn_mfma_f32_16x16x32_bf16(kf1, aq1, cB1, 0, 0, 0);
        __builtin_amdgcn_s_setprio(0);

        // Pack P: shorts [e(s0[0..3]) | e(s1[0..3])] = keys kb+8g+0..7 in order.
        union { unsigned u4[4]; bf16x8 v; } ap0, ap1;
        ap0.u4[0] = cvt_pk_bf16(__builtin_amdgcn_exp2f(s00[0]), __builtin_amdgcn_exp2f(s00[1]));
        ap0.u4[1] = cvt_pk_bf16(__builtin_amdgcn_exp2f(s00[2]), __builtin_amdgcn_exp2f(s00[3]));
        ap0.u4[2] = cvt_pk_bf16(__builtin_amdgcn_exp2f(s01[0]), __builtin_amdgcn_exp2f(s01[1]));
        ap0.u4[3] = cvt_pk_bf16(__builtin_amdgcn_exp2f(s01[2]), __builtin_amdgcn_exp2f(s01[3]));
        ap1.u4[0] = cvt_pk_bf16(__builtin_amdgcn_exp2f(s10[0]), __builtin_amdgcn_exp2f(s10[1]));
        ap1.u4[1] = cvt_pk_bf16(__builtin_amdgcn_exp2f(s10[2]), __builtin_amdgcn_exp2f(s10[3]));
        ap1.u4[2] = cvt_pk_bf16(__builtin_amdgcn_exp2f(s11[0]), __builtin_amdgcn_exp2f(s11[1]));
        ap1.u4[3] = cvt_pk_bf16(__builtin_amdgcn_exp2f(s11[2]), __builtin_amdgcn_exp2f(s11[3]));

        __builtin_amdgcn_s_setprio(1);
        o00 = __builtin_amdgcn_mfma_f32_16x16x32_bf16(ap0.v, vA0, o00, 0, 0, 0);
        o01 = __builtin_amdgcn_mfma_f32_16x16x32_bf16(ap0.v, vA1, o01, 0, 0, 0);
        ls0 = __builtin_amdgcn_mfma_f32_16x16x32_bf16(ap0.v, ones, ls0, 0, 0, 0);
        o10 = __builtin_amdgcn_mfma_f32_16x16x32_bf16(ap1.v, vA0, o10, 0, 0, 0);
        o11 = __builtin_amdgcn_mfma_f32_16x16x32_bf16(ap1.v, vA1, o11, 0, 0, 0);
        ls1 = __builtin_amdgcn_mfma_f32_16x16x32_bf16(ap1.v, ones, ls1, 0, 0, 0);
        __builtin_amdgcn_s_setprio(0);

        kf0 = nk0; kf1 = nk1;
        cA0 = nA0; cA1 = nA1; cB0 = nB0; cB1 = nB1;
    }

    #pragma unroll
    for (int r = 0; r < 4; ++r) {
        float i0 = 1.f / ls0[r], i1 = 1.f / ls1[r];
        o00[r] *= i0; o01[r] *= i0;
        o10[r] *= i1; o11[r] *= i1;
    }

    __syncthreads();   // all waves done with k_s; overlay otr on K region
    unsigned short (*otr)[32][40] = (unsigned short(*)[32][40])smem;
    #pragma unroll
    for (int r = 0; r < 4; ++r) {
        otr[wid][g * 4 + r][ln]           = f2bf(o00[r]);
        otr[wid][g * 4 + r][16 + ln]      = f2bf(o01[r]);
        otr[wid][16 + g * 4 + r][ln]      = f2bf(o10[r]);
        otr[wid][16 + g * 4 + r][16 + ln] = f2bf(o11[r]);
    }
    // same-wave region: DS in-order, no barrier.  2 lanes/row x 16 d each.
    const int row = lane >> 1;
    const int ch  = (lane & 1) * 16;
    uint4 st0 = *(uint4*)&otr[wid][row][ch];
    uint4 st1 = *(uint4*)&otr[wid][row][ch + 8];
    unsigned short* dst = &ao16[((size_t)b * NTOK + qb + row) * CDIM + h * HDIM + ch];
    *(uint4*)dst     = st0;
    *(uint4*)&dst[8] = st1;
}

// ---------------------------------------------------------------------------
// Output projection: 64c x 128p per block, wave = 2 c-frags x 4 p-frags.
// XCD-swizzled flat grid 512.
// ---------------------------------------------------------------------------
__global__ __launch_bounds__(256) void outproj_kernel(
    const unsigned short* __restrict__ ao16,  // (b,n,256)
    const unsigned short* __restrict__ wo16,  // (256,256)
    const float* __restrict__ bo,
    float* __restrict__ y)                    // (b,256,n)
{
    const int id   = blockIdx.x;              // 0..511
    const int b    = (id & 7) * 2 + ((id >> 3) & 1);
    const int rest = id >> 4;                 // 0..31
    const int ct   = (rest & 3) * 64;
    const int pt   = (rest >> 2) * 128;
    const int t = threadIdx.x, wid = t >> 6, lane = t & 63;
    const int g = lane >> 4, ln = lane & 15;
    const int cb2 = ct + (wid & 1) * 32;
    const int pb  = pt + (wid >> 1) * 64;
    const unsigned short* ab = ao16 + (size_t)b * NTOK * CDIM;

    f32x4 acc[2][4];
    #pragma unroll
    for (int n = 0; n < 2; ++n)
        #pragma unroll
        for (int m = 0; m < 4; ++m) acc[n][m] = (f32x4){0.f, 0.f, 0.f, 0.f};

    #pragma unroll
    for (int kt = 0; kt < CDIM; kt += 32) {
        bf16x8 aw[2], bx[4];
        #pragma unroll
        for (int n = 0; n < 2; ++n)
            aw[n] = *(const bf16x8*)&wo16[(size_t)(cb2 + n * 16 + ln) * CDIM + kt + g * 8];
        #pragma unroll
        for (int m = 0; m < 4; ++m)
            bx[m] = *(const bf16x8*)&ab[(size_t)(pb + m * 16 + ln) * CDIM + kt + g * 8];
        #pragma unroll
        for (int n = 0; n < 2; ++n)
            #pragma unroll
            for (int m = 0; m < 4; ++m)
                acc[n][m] = __builtin_amdgcn_mfma_f32_16x16x32_bf16(aw[n], bx[m], acc[n][m], 0, 0, 0);
    }
    #pragma unroll
    for (int n = 0; n < 2; ++n)
        #pragma unroll
        for (int r = 0; r < 4; ++r) {
            const int c = cb2 + n * 16 + g * 4 + r;
            const float bias = bo[c];
            #pragma unroll
            for (int m = 0; m < 4; ++m)
                y[((size_t)b * CDIM + c) * NTOK + pb + m * 16 + ln] = acc[n][m][r] + bias;
        }
}

// ---------------------------------------------------------------------------
extern "C" void kernel_launch(void* const* d_in, const int* in_sizes, int n_in,
                              void* d_out, int out_size, void* d_ws, size_t ws_size,
                              hipStream_t stream) {
    const float* x        = (const float*)d_in[0];
    const float* Wq       = (const float*)d_in[1];
    const float* Wk       = (const float*)d_in[2];
    const float* Wv       = (const float*)d_in[3];
    const float* Wo       = (const float*)d_in[4];
    const float* bo       = (const float*)d_in[5];
    const float* rel_bias = (const float*)d_in[6];
    (void)in_sizes; (void)n_in; (void)ws_size; (void)out_size;
    // d_in[7] = rel_idx: unused — bias index computed analytically (j - p + 1056)

    unsigned short* ws16 = (unsigned short*)d_ws;
    // Layout (shorts).  ao16 ALIASES xt16: xt16 is dead after qkv_kernel, and
    // the kernels are stream-ordered (prep -> qkv -> attn -> outproj).
    unsigned short* xt16 = ws16;                                   // 8 MB @ 0
    unsigned short* ao16 = ws16;                                   // alias @ 0
    unsigned short* w16  = ws16 + (size_t)4 * 1024 * 1024;         // 512 KB @ 8 MB
    unsigned short* q16  = w16 + 4 * 65536;                        // 8 MB @ 8.5 MB
    unsigned short* k16  = q16 + (size_t)4 * 1024 * 1024;          // 8 MB @ 16.5 MB
    unsigned short* v16  = k16 + (size_t)4 * 1024 * 1024;          // 8 MB @ 24.5 MB
    float* y = (float*)d_out;

    prep_kernel<<<dim3(16, 4, 17), 256, 0, stream>>>(x, Wq, Wk, Wv, Wo, w16, xt16);
    qkv_kernel<<<256, 1024, 0, stream>>>(xt16, w16, q16, k16, v16);
    attn_kernel<<<256, 1024, 0, stream>>>(q16, k16, v16, rel_bias, ao16);
    outproj_kernel<<<512, 256, 0, stream>>>(ao16, w16 + 3 * 65536, bo, y);
}

// Round 7
// 156.967 us; speedup vs baseline: 1.6661x; 1.0065x over previous
//
#include <hip/hip_runtime.h>

#define HEADS 8
#define HDIM 32
#define NTOK 1024
#define CDIM 256
#define BATCH 16
#define ATT_SCALE 0.17677669529663687f  // 32^-0.5
#define L2E 1.4426950408889634f
#define BSTR 1544   // bias copy stride (floats): 16B-aligned; 1544%32=8 -> ~2-way reads
#define XSTR 514    // qkv LDS x-tile row stride (f32): even (8B align) and 514%32=2
                    // -> column fragment reads land 2 lanes/bank = conflict-free

typedef __attribute__((ext_vector_type(8))) short bf16x8;   // 8 bf16, 4 VGPRs
typedef __attribute__((ext_vector_type(4))) float f32x4;    // MFMA C/D

__device__ __forceinline__ unsigned short f2bf(float f) {
    unsigned int u = __float_as_uint(f);
    return (unsigned short)((u + 0x7fffu + ((u >> 16) & 1u)) >> 16);  // RNE
}

// pack two f32 -> (bf16(lo) | bf16(hi)<<16) in one instruction; RNE == f2bf
__device__ __forceinline__ unsigned cvt_pk_bf16(float lo, float hi) {
    unsigned r;
    asm("v_cvt_pk_bf16_f32 %0, %1, %2" : "=v"(r) : "v"(lo), "v"(hi));
    return r;
}

// ---------------------------------------------------------------------------
// Weight prep only: fp32 -> bf16, Wk pre-scaled by ATT_SCALE*log2(e).
// (The x-transpose pass is gone -- qkv_kernel now reads x directly.)
// ---------------------------------------------------------------------------
__global__ __launch_bounds__(256) void prepw_kernel(
    const float* __restrict__ Wq, const float* __restrict__ Wk,
    const float* __restrict__ Wv, const float* __restrict__ Wo,
    unsigned short* __restrict__ w16)
{
    const int t = threadIdx.x;
    const int which = blockIdx.y;
    const float* src = (which == 0) ? Wq : ((which == 1) ? Wk : ((which == 2) ? Wv : Wo));
    const float scale = (which == 1) ? (ATT_SCALE * L2E) : 1.0f;
    const int base = (blockIdx.x * 256 + t) * 16;
    #pragma unroll
    for (int i = 0; i < 4; ++i) {
        const int idx = base + i * 4;
        float4 v = *(const float4*)&src[idx];
        union { unsigned short h[4]; uint2 u; } pk;
        pk.h[0] = f2bf(v.x * scale); pk.h[1] = f2bf(v.y * scale);
        pk.h[2] = f2bf(v.z * scale); pk.h[3] = f2bf(v.w * scale);
        *(uint2*)&w16[(size_t)which * 65536 + idx] = pk.u;
    }
}

// ---------------------------------------------------------------------------
// QKV GEMM with INTEGRATED x transpose.  Block = (b,h,token-half), 16 waves.
// Per 32-c chunk: stage x[kt..kt+32)[512 tokens] f32 -> LDS (lane-contiguous
// float2 writes, conflict-free), barrier, column-read 8 c per fragment
// (stride XSTR=514: 2 lanes/bank = free), cvt_pk -> bf16 (RNE, == f2bf ->
// bit-identical q/k/v vs the old xt16 path), 12 MFMA sharing x fragments.
// Eliminates the standalone transpose kernel and xt16's 96 MB round-trip.
// K/V written fragment-major (attn's LDS layout); Q row-major.
// ---------------------------------------------------------------------------
__global__ __launch_bounds__(1024, 4) void qkv_kernel(
    const float* __restrict__ x,              // (b,c,n) f32
    const unsigned short* __restrict__ w16,   // wq|wk|wv|wo (wk pre-scaled)
    unsigned short* __restrict__ q16,         // (b,n,h,32)
    unsigned short* __restrict__ k16,         // (b,h, 64 frag, 512)
    unsigned short* __restrict__ v16)         // (b,h, 64 frag, 512)
{
    __shared__ __align__(16) float lx[32 * XSTR];   // 64.25 KB

    const int id   = blockIdx.x;                    // 0..255
    const int bh_i = (id & 7) * 16 + (id >> 4);
    const int tokhalf = (id >> 3) & 1;
    const int b = bh_i >> 3, h = bh_i & 7;

    const int t = threadIdx.x, wid = t >> 6, lane = t & 63;
    const int g = lane >> 4, ln = lane & 15;
    const int trl = wid * 32;                       // wave's 32 tokens (block-local)
    const int tok0 = tokhalf * 512;

    const float* xb = x + (size_t)b * CDIM * NTOK;
    const unsigned short* wqh = w16 + (size_t)(h * 32) * CDIM;
    const unsigned short* wkh = w16 + 65536 + (size_t)(h * 32) * CDIM;
    const unsigned short* wvh = w16 + 2 * 65536 + (size_t)(h * 32) * CDIM;

    f32x4 aq[2][2], ak[2][2], av[2][2];
    #pragma unroll
    for (int m = 0; m < 2; ++m)
        #pragma unroll
        for (int n = 0; n < 2; ++n) {
            aq[m][n] = (f32x4){0.f, 0.f, 0.f, 0.f};
            ak[m][n] = (f32x4){0.f, 0.f, 0.f, 0.f};
            av[n][m] = (f32x4){0.f, 0.f, 0.f, 0.f};
        }

    const int scc = t >> 7;          // staging c-row within octet (0..7)
    const int sn0 = (t & 127) * 4;   // staging token offset (one float4)

    for (int kt = 0; kt < CDIM; kt += 32) {
        if (kt) __syncthreads();     // prior chunk's reads done before overwrite
        // ---- stage: 32 c-rows x 512 tokens, f32 (coalesced 2KB per 128 thr) ----
        #pragma unroll
        for (int p = 0; p < 4; ++p) {
            const int cc = scc + 8 * p;
            const float4 v = *(const float4*)&xb[(size_t)(kt + cc) * NTOK + tok0 + sn0];
            *(float2*)&lx[cc * XSTR + sn0]     = make_float2(v.x, v.y);
            *(float2*)&lx[cc * XSTR + sn0 + 2] = make_float2(v.z, v.w);
        }
        __syncthreads();
        // ---- fragments: column reads (8 c per token), cvt_pk -> bf16 ----
        bf16x8 xf[2];
        #pragma unroll
        for (int m = 0; m < 2; ++m) {
            const float* col = &lx[(size_t)(g * 8) * XSTR + trl + m * 16 + ln];
            union { unsigned u4[4]; bf16x8 v; } pk;
            #pragma unroll
            for (int p = 0; p < 4; ++p)
                pk.u4[p] = cvt_pk_bf16(col[(2 * p) * XSTR], col[(2 * p + 1) * XSTR]);
            xf[m] = pk.v;
        }
        bf16x8 wqf[2], wkf[2], wvf[2];
        #pragma unroll
        for (int n = 0; n < 2; ++n) {
            wqf[n] = *(const bf16x8*)&wqh[(size_t)(n * 16 + ln) * CDIM + kt + g * 8];
            wkf[n] = *(const bf16x8*)&wkh[(size_t)(n * 16 + ln) * CDIM + kt + g * 8];
            wvf[n] = *(const bf16x8*)&wvh[(size_t)(n * 16 + ln) * CDIM + kt + g * 8];
        }
        #pragma unroll
        for (int m = 0; m < 2; ++m)
            #pragma unroll
            for (int n = 0; n < 2; ++n) {
                aq[m][n] = __builtin_amdgcn_mfma_f32_16x16x32_bf16(xf[m], wqf[n], aq[m][n], 0, 0, 0);
                ak[m][n] = __builtin_amdgcn_mfma_f32_16x16x32_bf16(xf[m], wkf[n], ak[m][n], 0, 0, 0);
                av[n][m] = __builtin_amdgcn_mfma_f32_16x16x32_bf16(wvf[n], xf[m], av[n][m], 0, 0, 0);
            }
    }

    const int tr = tok0 + trl;
    // Q store, row-major (b,n,h,32).  aq[m][n][r] = Q[row=tr+m*16+g*4+r][col=n*16+ln].
    #pragma unroll
    for (int m = 0; m < 2; ++m)
        #pragma unroll
        for (int n = 0; n < 2; ++n)
            #pragma unroll
            for (int r = 0; r < 4; ++r)
                q16[((size_t)(b * NTOK + tr + m * 16 + g * 4 + r) * 8 + h) * 32 + n * 16 + ln] =
                    f2bf(aq[m][n][r]);

    // K store, fragment-major.
    unsigned short* kb16 = k16 + (size_t)(b * 8 + h) * 32768;
    const int fK = (tokhalf * 16 + wid) * 2 + (g & 1);
    #pragma unroll
    for (int m = 0; m < 2; ++m)
        #pragma unroll
        for (int n = 0; n < 2; ++n) {
            const int lhi = (2 * n + (ln >> 3)) * 16 + (m * 2 + (g >> 1)) * 4;
            #pragma unroll
            for (int r = 0; r < 4; ++r)
                kb16[fK * 512 + (lhi + r) * 8 + (ln & 7)] = f2bf(ak[m][n][r]);
        }

    // V store, fragment-major.  av[n][m][r] = V[d=n*16+g*4+r][tok=tr+m*16+ln].
    unsigned short* vb16 = v16 + (size_t)(b * 8 + h) * 32768;
    #pragma unroll
    for (int n = 0; n < 2; ++n) {
        const int fV = (tokhalf * 16 + wid) * 2 + n;
        #pragma unroll
        for (int m = 0; m < 2; ++m) {
            const int lnb = (m * 2 + (ln >> 3)) * 16 + g * 4;
            #pragma unroll
            for (int r = 0; r < 4; ++r)
                vb16[fV * 512 + (lnb + r) * 8 + (ln & 7)] = f2bf(av[n][m][r]);
        }
    }
}

// ---------------------------------------------------------------------------
// Flash attention.  Block = (b, h, query-half): 1024 thr/16 waves.
// (Unchanged from R6 -- proven schedule.)
// ---------------------------------------------------------------------------
__global__ __launch_bounds__(1024, 4) void attn_kernel(
    const unsigned short* __restrict__ q16,   // (b,n,h,32)
    const unsigned short* __restrict__ k16,   // (b,h,64,512) frag-major
    const unsigned short* __restrict__ v16,   // (b,h,64,512) frag-major
    const float* __restrict__ rel_bias,       // (h, 3969)
    unsigned short* __restrict__ ao16)        // (b, n, 256)
{
    __shared__ __align__(16) unsigned char smem[65536 + 65536 + BSTR * 4 * 4];
    unsigned short* k_s   = (unsigned short*)smem;             // 64 frags x 512 shorts
    unsigned short* v_s   = (unsigned short*)(smem + 65536);   // 64 frags x 512 shorts
    float*          bias4 = (float*)(smem + 131072);           // [4][BSTR]

    const int id   = blockIdx.x;                    // 0..255
    const int bh_i = (id & 7) * 16 + (id >> 4);     // XCD x owns bh [16x,16x+16)
    const int half = (id >> 3) & 1;
    const int b = bh_i >> 3, h = bh_i & 7;

    const int t = threadIdx.x, wid = t >> 6, lane = t & 63;
    const int g = lane >> 4, ln = lane & 15;
    const int qb = half * 512 + wid * 32;           // wave's 32 queries

    const unsigned short* kbh = k16 + (size_t)(b * 8 + h) * 32768;
    const unsigned short* vbh = v16 + (size_t)(b * 8 + h) * 32768;

    // ---- stage K/V fragments: global -> reg (issue early) ----
    bf16x8 sk[4], sv[4];
    #pragma unroll
    for (int j = 0; j < 4; ++j) {
        const int f = wid * 4 + j;
        sk[j] = *(const bf16x8*)&kbh[(size_t)f * 512 + lane * 8];
        sv[j] = *(const bf16x8*)&vbh[(size_t)f * 512 + lane * 8];
    }
    // ---- Q fragments ----
    const bf16x8 aq0 = *(const bf16x8*)&q16[((size_t)(b * NTOK + qb + ln) * 8 + h) * 32 + g * 8];
    const bf16x8 aq1 = *(const bf16x8*)&q16[((size_t)(b * NTOK + qb + 16 + ln) * 8 + h) * 32 + g * 8];

    // ---- bias*log2e -> 4 shift-aligned copies (overlaps the loads above) ----
    {
        const int START = 544 - 512 * half;         // 4-aligned window base
        const float* brow = rel_bias + (size_t)h * 3969;
        for (int i = t; i < 1540; i += 1024) {
            #pragma unroll
            for (int a = 0; a < 4; ++a)
                bias4[a * BSTR + i] = brow[START + a + i] * L2E;
        }
    }

    // ---- commit staged frags to LDS (linear in lane = conflict-free) ----
    #pragma unroll
    for (int j = 0; j < 4; ++j) {
        const int f = wid * 4 + j;
        *(bf16x8*)&k_s[(size_t)f * 512 + lane * 8] = sk[j];
        *(bf16x8*)&v_s[(size_t)f * 512 + lane * 8] = sv[j];
    }

    __syncthreads();   // K, V, bias all LDS-resident

    // ---- Stage 2: attention main loop (R1 schedule, verbatim) ----
    const int boffL = 512 + 8 * g - wid * 32 - ln;   // local bias offset
    const int ba = boffL & 3;
    const float* bb = &bias4[ba * BSTR + (boffL - ba)];
    const unsigned short* kfp = k_s + lane * 8;      // frag stride 512 shorts
    const unsigned short* vfp = v_s + lane * 8;

    f32x4 o00 = {0.f,0.f,0.f,0.f}, o01 = {0.f,0.f,0.f,0.f};
    f32x4 o10 = {0.f,0.f,0.f,0.f}, o11 = {0.f,0.f,0.f,0.f};
    f32x4 ls0 = {0.f,0.f,0.f,0.f}, ls1 = {0.f,0.f,0.f,0.f};
    const short one_bf = (short)0x3F80;
    const bf16x8 ones = {one_bf,one_bf,one_bf,one_bf,one_bf,one_bf,one_bf,one_bf};

    // prologue: iter-0 K fragments + bias C-operands
    bf16x8 kf0 = *(const bf16x8*)&kfp[0];
    bf16x8 kf1 = *(const bf16x8*)&kfp[512];
    f32x4  cA0 = *(const f32x4*)&bb[0];
    f32x4  cA1 = *(const f32x4*)&bb[4];
    f32x4  cB0 = *(const f32x4*)&bb[-16];
    f32x4  cB1 = *(const f32x4*)&bb[-12];

    for (int kb = 0; kb < NTOK; kb += 32) {
        const int fi = (kb >> 5) * 2;
        // V for THIS iter: consumed only after S-MFMA + exp chain -> self-hiding.
        const bf16x8 vA0 = *(const bf16x8*)&vfp[fi * 512];
        const bf16x8 vA1 = *(const bf16x8*)&vfp[(fi + 1) * 512];
        // prefetch NEXT iter's K + bias (wrap keeps addresses in-bounds).
        const int kn = (kb + 32) & (NTOK - 1);
        const int fn = (kn >> 5) * 2;
        const bf16x8 nk0 = *(const bf16x8*)&kfp[fn * 512];
        const bf16x8 nk1 = *(const bf16x8*)&kfp[(fn + 1) * 512];
        const f32x4  nA0 = *(const f32x4*)&bb[kn];
        const f32x4  nA1 = *(const f32x4*)&bb[kn + 4];
        const f32x4  nB0 = *(const f32x4*)&bb[kn - 16];
        const f32x4  nB1 = *(const f32x4*)&bb[kn - 12];

        __builtin_amdgcn_s_setprio(1);
        f32x4 s00 = __builtin_amdgcn_mfma_f32_16x16x32_bf16(kf0, aq0, cA0, 0, 0, 0);
        f32x4 s01 = __builtin_amdgcn_mfma_f32_16x16x32_bf16(kf1, aq0, cA1, 0, 0, 0);
        f32x4 s10 = __builtin_amdgcn_mfma_f32_16x16x32_bf16(kf0, aq1, cB0, 0, 0, 0);
        f32x4 s11 = __builtin_amdgcn_mfma_f32_16x16x32_bf16(kf1, aq1, cB1, 0, 0, 0);
        __builtin_amdgcn_s_setprio(0);

        // Pack P: shorts [e(s0[0..3]) | e(s1[0..3])] = keys kb+8g+0..7 in order.
        union { unsigned u4[4]; bf16x8 v; } ap0, ap1;
        ap0.u4[0] = cvt_pk_bf16(__builtin_amdgcn_exp2f(s00[0]), __builtin_amdgcn_exp2f(s00[1]));
        ap0.u4[1] = cvt_pk_bf16(__builtin_amdgcn_exp2f(s00[2]), __builtin_amdgcn_exp2f(s00[3]));
        ap0.u4[2] = cvt_pk_bf16(__builtin_amdgcn_exp2f(s01[0]), __builtin_amdgcn_exp2f(s01[1]));
        ap0.u4[3] = cvt_pk_bf16(__builtin_amdgcn_exp2f(s01[2]), __builtin_amdgcn_exp2f(s01[3]));
        ap1.u4[0] = cvt_pk_bf16(__builtin_amdgcn_exp2f(s10[0]), __builtin_amdgcn_exp2f(s10[1]));
        ap1.u4[1] = cvt_pk_bf16(__builtin_amdgcn_exp2f(s10[2]), __builtin_amdgcn_exp2f(s10[3]));
        ap1.u4[2] = cvt_pk_bf16(__builtin_amdgcn_exp2f(s11[0]), __builtin_amdgcn_exp2f(s11[1]));
        ap1.u4[3] = cvt_pk_bf16(__builtin_amdgcn_exp2f(s11[2]), __builtin_amdgcn_exp2f(s11[3]));

        __builtin_amdgcn_s_setprio(1);
        o00 = __builtin_amdgcn_mfma_f32_16x16x32_bf16(ap0.v, vA0, o00, 0, 0, 0);
        o01 = __builtin_amdgcn_mfma_f32_16x16x32_bf16(ap0.v, vA1, o01, 0, 0, 0);
        ls0 = __builtin_amdgcn_mfma_f32_16x16x32_bf16(ap0.v, ones, ls0, 0, 0, 0);
        o10 = __builtin_amdgcn_mfma_f32_16x16x32_bf16(ap1.v, vA0, o10, 0, 0, 0);
        o11 = __builtin_amdgcn_mfma_f32_16x16x32_bf16(ap1.v, vA1, o11, 0, 0, 0);
        ls1 = __builtin_amdgcn_mfma_f32_16x16x32_bf16(ap1.v, ones, ls1, 0, 0, 0);
        __builtin_amdgcn_s_setprio(0);

        kf0 = nk0; kf1 = nk1;
        cA0 = nA0; cA1 = nA1; cB0 = nB0; cB1 = nB1;
    }

    #pragma unroll
    for (int r = 0; r < 4; ++r) {
        float i0 = 1.f / ls0[r], i1 = 1.f / ls1[r];
        o00[r] *= i0; o01[r] *= i0;
        o10[r] *= i1; o11[r] *= i1;
    }

    __syncthreads();   // all waves done with k_s; overlay otr on K region
    unsigned short (*otr)[32][40] = (unsigned short(*)[32][40])smem;
    #pragma unroll
    for (int r = 0; r < 4; ++r) {
        otr[wid][g * 4 + r][ln]           = f2bf(o00[r]);
        otr[wid][g * 4 + r][16 + ln]      = f2bf(o01[r]);
        otr[wid][16 + g * 4 + r][ln]      = f2bf(o10[r]);
        otr[wid][16 + g * 4 + r][16 + ln] = f2bf(o11[r]);
    }
    // same-wave region: DS in-order, no barrier.  2 lanes/row x 16 d each.
    const int row = lane >> 1;
    const int ch  = (lane & 1) * 16;
    uint4 st0 = *(uint4*)&otr[wid][row][ch];
    uint4 st1 = *(uint4*)&otr[wid][row][ch + 8];
    unsigned short* dst = &ao16[((size_t)b * NTOK + qb + row) * CDIM + h * HDIM + ch];
    *(uint4*)dst     = st0;
    *(uint4*)&dst[8] = st1;
}

// ---------------------------------------------------------------------------
// Output projection: 64c x 128p per block, wave = 2 c-frags x 4 p-frags.
// XCD-swizzled flat grid 512.  (Unchanged from R6.)
// ---------------------------------------------------------------------------
__global__ __launch_bounds__(256) void outproj_kernel(
    const unsigned short* __restrict__ ao16,  // (b,n,256)
    const unsigned short* __restrict__ wo16,  // (256,256)
    const float* __restrict__ bo,
    float* __restrict__ y)                    // (b,256,n)
{
    const int id   = blockIdx.x;              // 0..511
    const int b    = (id & 7) * 2 + ((id >> 3) & 1);
    const int rest = id >> 4;                 // 0..31
    const int ct   = (rest & 3) * 64;
    const int pt   = (rest >> 2) * 128;
    const int t = threadIdx.x, wid = t >> 6, lane = t & 63;
    const int g = lane >> 4, ln = lane & 15;
    const int cb2 = ct + (wid & 1) * 32;
    const int pb  = pt + (wid >> 1) * 64;
    const unsigned short* ab = ao16 + (size_t)b * NTOK * CDIM;

    f32x4 acc[2][4];
    #pragma unroll
    for (int n = 0; n < 2; ++n)
        #pragma unroll
        for (int m = 0; m < 4; ++m) acc[n][m] = (f32x4){0.f, 0.f, 0.f, 0.f};

    #pragma unroll
    for (int kt = 0; kt < CDIM; kt += 32) {
        bf16x8 aw[2], bx[4];
        #pragma unroll
        for (int n = 0; n < 2; ++n)
            aw[n] = *(const bf16x8*)&wo16[(size_t)(cb2 + n * 16 + ln) * CDIM + kt + g * 8];
        #pragma unroll
        for (int m = 0; m < 4; ++m)
            bx[m] = *(const bf16x8*)&ab[(size_t)(pb + m * 16 + ln) * CDIM + kt + g * 8];
        #pragma unroll
        for (int n = 0; n < 2; ++n)
            #pragma unroll
            for (int m = 0; m < 4; ++m)
                acc[n][m] = __builtin_amdgcn_mfma_f32_16x16x32_bf16(aw[n], bx[m], acc[n][m], 0, 0, 0);
    }
    #pragma unroll
    for (int n = 0; n < 2; ++n)
        #pragma unroll
        for (int r = 0; r < 4; ++r) {
            const int c = cb2 + n * 16 + g * 4 + r;
            const float bias = bo[c];
            #pragma unroll
            for (int m = 0; m < 4; ++m)
                y[((size_t)b * CDIM + c) * NTOK + pb + m * 16 + ln] = acc[n][m][r] + bias;
        }
}

// ---------------------------------------------------------------------------
extern "C" void kernel_launch(void* const* d_in, const int* in_sizes, int n_in,
                              void* d_out, int out_size, void* d_ws, size_t ws_size,
                              hipStream_t stream) {
    const float* x        = (const float*)d_in[0];
    const float* Wq       = (const float*)d_in[1];
    const float* Wk       = (const float*)d_in[2];
    const float* Wv       = (const float*)d_in[3];
    const float* Wo       = (const float*)d_in[4];
    const float* bo       = (const float*)d_in[5];
    const float* rel_bias = (const float*)d_in[6];
    (void)in_sizes; (void)n_in; (void)ws_size; (void)out_size;
    // d_in[7] = rel_idx: unused — bias index computed analytically (j - p + 1056)

    unsigned short* ws16 = (unsigned short*)d_ws;
    unsigned short* w16  = ws16;                                   // 512 KB
    unsigned short* q16  = ws16 + 4 * 65536;                       // 8 MB
    unsigned short* k16  = q16 + (size_t)4 * 1024 * 1024;          // 8 MB
    unsigned short* v16  = k16 + (size_t)4 * 1024 * 1024;          // 8 MB
    unsigned short* ao16 = v16 + (size_t)4 * 1024 * 1024;          // 8 MB
    float* y = (float*)d_out;

    prepw_kernel<<<dim3(16, 4), 256, 0, stream>>>(Wq, Wk, Wv, Wo, w16);
    qkv_kernel<<<256, 1024, 0, stream>>>(x, w16, q16, k16, v16);
    attn_kernel<<<256, 1024, 0, stream>>>(q16, k16, v16, rel_bias, ao16);
    outproj_kernel<<<512, 256, 0, stream>>>(ao16, w16 + 3 * 65536, bo, y);
}